// Round 2
// baseline (19868.704 us; speedup 1.0000x reference)
//
#include <hip/hip_runtime.h>
#include <hip/hip_cooperative_groups.h>
#include <math.h>

namespace cg = cooperative_groups;

#define TT   256
#define BB   1024
#define YDIM 32
#define HDIM 1024
#define RDIM 512

typedef __attribute__((ext_vector_type(8))) short frag8;
typedef __attribute__((ext_vector_type(4))) float f32x4;

#define LDS_BUF 16384  // shorts per double-buffer half: (128 A rows + 128 B rows) x 64

// ---------------- workspace layout (bytes) ----------------
#define OFF_NLL   ((size_t)0)
#define OFF_HAF   ((size_t)4096)                     // fp32 h0 x2 (state; fallback path only)
#define SZ_HF     ((size_t)BB*RDIM*4)
#define OFF_HBF   (OFF_HAF + 2*SZ_HF)                // fp32 h1 x2
#define OFF_HA16  (OFF_HBF + 2*SZ_HF)                // bf16 h0 x2 (GEMM operand copy)
#define SZ_H16    ((size_t)BB*RDIM*2)
#define OFF_HB16  (OFF_HA16 + 2*SZ_H16)              // bf16 h1 x2
#define OFF_D1    (OFF_HB16 + 2*SZ_H16)              // bf16 d1 x2
#define SZ_DBUF   ((size_t)BB*HDIM*2)
#define OFF_D2    (OFF_D1 + 2*SZ_DBUF)               // bf16 d2 x2
#define OFF_Y16   (OFF_D2 + 2*SZ_DBUF)               // bf16 y [T,B,32]
#define OFF_WG0I  (OFF_Y16 + (size_t)TT*BB*YDIM*2)
#define OFF_WG0H  (OFF_WG0I + (size_t)1536*YDIM*2)
#define OFF_WG1I  (OFF_WG0H + (size_t)1536*RDIM*2)
#define OFF_WG1H  (OFF_WG1I + (size_t)1536*RDIM*2)
#define OFF_WD1   (OFF_WG1H + (size_t)1536*RDIM*2)
#define OFF_WD2   (OFF_WD1 + (size_t)HDIM*RDIM*2)
#define OFF_WMS   (OFF_WD2 + (size_t)HDIM*HDIM*2)
#define OFF_BI0   (OFF_WMS + (size_t)64*HDIM*2)
#define OFF_BH0   (OFF_BI0 + 1536*4)
#define OFF_BI1   (OFF_BH0 + 1536*4)
#define OFF_BH1   (OFF_BI1 + 1536*4)

__device__ __forceinline__ short f2bf(float f) {
  union { float f; unsigned u; } v; v.f = f;
  unsigned r = (v.u + 0x7fffu + ((v.u >> 16) & 1u)) >> 16;
  return (short)r;
}
__device__ __forceinline__ void cvt8(const float* s, short* d) {
  float4 a = *(const float4*)s;
  float4 b = *(const float4*)(s + 4);
  frag8 v;
  v[0]=f2bf(a.x); v[1]=f2bf(a.y); v[2]=f2bf(a.z); v[3]=f2bf(a.w);
  v[4]=f2bf(b.x); v[5]=f2bf(b.y); v[6]=f2bf(b.z); v[7]=f2bf(b.w);
  *(frag8*)d = v;
}
// gate-interleaved row permutation: packed row n = q*48 + g*16 + u  <->  src row g*512 + q*16 + u
__device__ __forceinline__ int permRow(int n) {
  int q = n / 48, r = n - 48 * q, g = r >> 4, u = r & 15;
  return g * 512 + q * 16 + u;
}
__device__ __forceinline__ float sigf(float x) { return 1.0f / (1.0f + expf(-x)); }

// async 16B global -> LDS (dest = uniform base + lane*16)
__device__ __forceinline__ void gload16(const short* g, short* l) {
  __builtin_amdgcn_global_load_lds(
      (const __attribute__((address_space(1))) void*)g,
      (__attribute__((address_space(3))) void*)l, 16, 0, 0);
}

// ---------------- double-buffered MFMA K-loop, 64-wide chunks ----------------
template<int MF, int NF>
__device__ __forceinline__ void kloop64(
    const short* __restrict__ A, int lda, int m0,
    const short* __restrict__ B, int ldb, int nrowsB, int K,
    int wm, int wn, short* lds, f32x4 (*acc)[NF], int tid)
{
  const int l = tid & 63, w = tid >> 6, u = l & 15, quad = l >> 4;
  const int nk = K >> 6;
  const int bunits = nrowsB << 3;

  auto stage = [&](int kc, int buf) {
    short* base = lds + buf * LDS_BUF;
    const int k0 = kc << 6;
    for (int c = (w << 6); c < 1024; c += 256) {
      int p = c + l, r = p >> 3, q = (p & 7) ^ (r & 7);
      gload16(A + (size_t)(m0 + r) * lda + k0 + (q << 3), base + (c << 3));
    }
    short* bb = base + 8192;
    for (int c = (w << 6); c < bunits; c += 256) {
      int p = c + l, r = p >> 3, q = (p & 7) ^ (r & 7);
      gload16(B + (size_t)r * ldb + k0 + (q << 3), bb + (c << 3));
    }
  };

  stage(0, 0);
  __syncthreads();
  for (int kc = 0; kc < nk; ++kc) {
    if (kc + 1 < nk) stage(kc + 1, (kc + 1) & 1);   // overlaps compute below
    const short* base = lds + (kc & 1) * LDS_BUF;
#pragma unroll
    for (int kk2 = 0; kk2 < 2; ++kk2) {
      const int q = (kk2 << 2) + quad;
      const int aoff = (q ^ (u & 7)) << 3;
      frag8 a[MF], b[NF];
#pragma unroll
      for (int i = 0; i < MF; ++i)
        a[i] = *(const frag8*)(base + ((wm + (i << 4) + u) << 6) + aoff);
#pragma unroll
      for (int f = 0; f < NF; ++f)
        b[f] = *(const frag8*)(base + 8192 + ((wn + (f << 4) + u) << 6) + aoff);
#pragma unroll
      for (int i = 0; i < MF; ++i)
#pragma unroll
        for (int f = 0; f < NF; ++f)
          acc[i][f] = __builtin_amdgcn_mfma_f32_16x16x32_bf16(a[i], b[f], acc[i][f], 0, 0, 0);
    }
    __syncthreads();  // drains stage(kc+1) loads (vmcnt 0) + guards buffer reuse
  }
}

// single 32-wide chunk (GRU layer0 gi, K=32)
template<int MF, int NF>
__device__ __forceinline__ void kloop32(
    const short* __restrict__ A, int lda, int m0,
    const short* __restrict__ B, int nrowsB,
    int wm, int wn, short* lds, f32x4 (*acc)[NF], int tid)
{
  const int l = tid & 63, w = tid >> 6, u = l & 15, quad = l >> 4;
  short* base = lds;
  for (int c = (w << 6); c < 512; c += 256) {
    int p = c + l, r = p >> 2, q = (p & 3) ^ (r & 3);
    gload16(A + (size_t)(m0 + r) * lda + (q << 3), base + (c << 3));
  }
  short* bb = base + 4096;
  const int bunits = nrowsB << 2;
  for (int c = (w << 6); c < bunits; c += 256) {
    int p = c + l, r = p >> 2, q = (p & 3) ^ (r & 3);
    gload16(B + (size_t)r * 32 + (q << 3), bb + (c << 3));
  }
  __syncthreads();
  const int aoff = (quad ^ (u & 3)) << 3;
  frag8 a[MF], b[NF];
#pragma unroll
  for (int i = 0; i < MF; ++i)
    a[i] = *(const frag8*)(base + ((wm + (i << 4) + u) << 5) + aoff);
#pragma unroll
  for (int f = 0; f < NF; ++f)
    b[f] = *(const frag8*)(base + 4096 + ((wn + (f << 4) + u) << 5) + aoff);
#pragma unroll
  for (int i = 0; i < MF; ++i)
#pragma unroll
    for (int f = 0; f < NF; ++f)
      acc[i][f] = __builtin_amdgcn_mfma_f32_16x16x32_bf16(a[i], b[f], acc[i][f], 0, 0, 0);
  __syncthreads();
}

// ---------------- GRU tile ----------------
// RS: keep fp32 h state in 16 VGPRs (persistent mega-kernel path); else memory.
template<bool GI32, bool RS>
__device__ void gru_tile(int mb, int nb,
                         const short* Ax, int ldx, const short* Wgi,
                         const short* Ah, const short* Wgh,
                         const float* bi, const float* bh,
                         const float* hold, float* hout, float* hreg,
                         short* h16out, short* lds, int tid)
{
  f32x4 zero = {0.f, 0.f, 0.f, 0.f};
  f32x4 gi[4][3], gh[4][3];
#pragma unroll
  for (int i = 0; i < 4; ++i)
#pragma unroll
    for (int f = 0; f < 3; ++f) { gi[i][f] = zero; gh[i][f] = zero; }
  const int w = tid >> 6, l = tid & 63, u = l & 15, quad = l >> 4;
  const int wm = (w & 1) * 64, wn = (w >> 1) * 48;
  if (GI32)
    kloop32<4, 3>(Ax, ldx, mb * 128, Wgi, 96, wm, wn, lds, gi, tid);
  else
    kloop64<4, 3>(Ax, ldx, mb * 128, Wgi, RDIM, 96, RDIM, wm, wn, lds, gi, tid);
  kloop64<4, 3>(Ah, RDIM, mb * 128, Wgh, RDIM, 96, RDIM, wm, wn, lds, gh, tid);

  const int np = nb * 96 + (w >> 1) * 48 + u;
  const float bir = bi[np], biz = bi[np + 16], bin = bi[np + 32];
  const float bhr = bh[np], bhz = bh[np + 16], bhn = bh[np + 32];
  const int unit = nb * 32 + (w >> 1) * 16 + u;
#pragma unroll
  for (int i = 0; i < 4; ++i)
#pragma unroll
    for (int j = 0; j < 4; ++j) {
      int row = mb * 128 + wm + 16 * i + quad * 4 + j;
      float r = sigf((gi[i][0][j] + bir) + (gh[i][0][j] + bhr));
      float z = sigf((gi[i][1][j] + biz) + (gh[i][1][j] + bhz));
      float n = tanhf((gi[i][2][j] + bin) + r * (gh[i][2][j] + bhn));
      float ho = RS ? hreg[i * 4 + j] : hold[(size_t)row * RDIM + unit];
      float hn = (1.f - z) * n + z * ho;
      if (RS) hreg[i * 4 + j] = hn;
      else    hout[(size_t)row * RDIM + unit] = hn;
      h16out[(size_t)row * RDIM + unit] = f2bf(hn);
    }
}

// ---------------- decoder Linear+ReLU tile (128x128) ----------------
__device__ void dec_tile(int mb, int nb, const short* A, int lda, int K,
                         const short* W, const float* bias, short* outp,
                         short* lds, int tid)
{
  f32x4 zero = {0.f, 0.f, 0.f, 0.f};
  f32x4 acc[4][4];
#pragma unroll
  for (int i = 0; i < 4; ++i)
#pragma unroll
    for (int f = 0; f < 4; ++f) acc[i][f] = zero;
  const int w = tid >> 6, l = tid & 63, u = l & 15, quad = l >> 4;
  const int wm = (w & 1) * 64, wn = (w >> 1) * 64;
  kloop64<4, 4>(A, lda, mb * 128, W, K, 128, K, wm, wn, lds, acc, tid);
  const int colb = nb * 128 + wn + u;
  float bv[4];
#pragma unroll
  for (int f = 0; f < 4; ++f) bv[f] = bias[colb + 16 * f];
#pragma unroll
  for (int i = 0; i < 4; ++i)
#pragma unroll
    for (int f = 0; f < 4; ++f)
#pragma unroll
      for (int j = 0; j < 4; ++j) {
        int row = mb * 128 + wm + 16 * i + quad * 4 + j;
        float v = acc[i][f][j] + bv[f];
        if (v < 0.f) v = 0.f;
        outp[(size_t)row * HDIM + colb + 16 * f] = f2bf(v);
      }
}

// ---------------- mean/std + gaussian NLL tile ----------------
__device__ void ms_tile(int mb, int tstep, const short* d2p, const short* Wms,
                        const float* mbias, const float* sbias, const float* y,
                        float* nll, short* lds, int tid)
{
  f32x4 zero = {0.f, 0.f, 0.f, 0.f};
  f32x4 acc[2][4];
#pragma unroll
  for (int i = 0; i < 2; ++i)
#pragma unroll
    for (int f = 0; f < 4; ++f) acc[i][f] = zero;
  const int w = tid >> 6, l = tid & 63, u = l & 15, quad = l >> 4;
  kloop64<2, 4>(d2p, HDIM, mb * 128, Wms, HDIM, 64, HDIM, w * 32, 0, lds, acc, tid);
  float lsum = 0.f;
#pragma unroll
  for (int i = 0; i < 2; ++i)
#pragma unroll
    for (int j = 0; j < 4; ++j) {
      int row = mb * 128 + w * 32 + 16 * i + quad * 4 + j;
      const float* yr = y + ((size_t)tstep * BB + row) * YDIM;
#pragma unroll
      for (int f = 0; f < 2; ++f) {
        int c = 16 * f + u;
        float m  = acc[i][f][j] + mbias[c];
        float sp = acc[i][f + 2][j] + sbias[c];
        float sg = (sp > 20.f) ? sp : log1pf(expf(sp));
        float dv = (yr[c] - m) / sg;
        lsum += dv * dv + 2.f * logf(sg) + 1.8378770664093453f;
      }
    }
  lsum *= 0.5f;
#pragma unroll
  for (int o = 32; o; o >>= 1) lsum += __shfl_xor(lsum, o);
  if (l == 0) atomicAdd(nll, lsum);
}

// ---------------- prepack ----------------
__global__ __launch_bounds__(256) void prepack_kernel(
    const float* y, const float* dw1, const float* dw2,
    const float* mw, const float* sw,
    const float* wih0, const float* whh0, const float* bih0, const float* bhh0,
    const float* wih1, const float* whh1, const float* bih1, const float* bhh1,
    char* __restrict__ ws)
{
  const size_t g = (size_t)blockIdx.x * 256 + threadIdx.x;
  const size_t N = (size_t)gridDim.x * 256;
  float4 z4 = {0.f, 0.f, 0.f, 0.f};
  float4* hz = (float4*)(ws + OFF_HAF);
  for (size_t i = g; i < (size_t)4 * BB * RDIM / 4; i += N) hz[i] = z4;
  int4 zi = {0, 0, 0, 0};
  int4* h16z = (int4*)(ws + OFF_HA16);
  for (size_t i = g; i < (size_t)4 * BB * RDIM / 8; i += N) h16z[i] = zi;
  if (g == 0) *(float*)(ws + OFF_NLL) = 0.f;

  short* y16  = (short*)(ws + OFF_Y16);
  short* Wg0i = (short*)(ws + OFF_WG0I);
  short* Wg0h = (short*)(ws + OFF_WG0H);
  short* Wg1i = (short*)(ws + OFF_WG1I);
  short* Wg1h = (short*)(ws + OFF_WG1H);
  short* Wd1  = (short*)(ws + OFF_WD1);
  short* Wd2  = (short*)(ws + OFF_WD2);
  short* Wms  = (short*)(ws + OFF_WMS);
  float* bi0  = (float*)(ws + OFF_BI0);
  float* bh0  = (float*)(ws + OFF_BH0);
  float* bi1  = (float*)(ws + OFF_BI1);
  float* bh1  = (float*)(ws + OFF_BH1);

  for (size_t s = g; s < (size_t)TT * BB * YDIM / 8; s += N)
    cvt8(y + s * 8, y16 + s * 8);
  for (size_t s = g; s < (size_t)1536 * RDIM / 8; s += N) {
    int row = (int)(s >> 6), seg = (int)(s & 63) << 3;
    int pr = permRow(row);
    cvt8(whh0 + (size_t)pr * RDIM + seg, Wg0h + (size_t)row * RDIM + seg);
    cvt8(wih1 + (size_t)pr * RDIM + seg, Wg1i + (size_t)row * RDIM + seg);
    cvt8(whh1 + (size_t)pr * RDIM + seg, Wg1h + (size_t)row * RDIM + seg);
  }
  for (size_t s = g; s < (size_t)1536 * YDIM / 8; s += N) {
    int row = (int)(s >> 2), seg = (int)(s & 3) << 3;
    cvt8(wih0 + (size_t)permRow(row) * YDIM + seg, Wg0i + (size_t)row * YDIM + seg);
  }
  for (size_t s = g; s < (size_t)HDIM * RDIM / 8; s += N)
    cvt8(dw1 + s * 8, Wd1 + s * 8);
  for (size_t s = g; s < (size_t)HDIM * HDIM / 8; s += N)
    cvt8(dw2 + s * 8, Wd2 + s * 8);
  for (size_t s = g; s < (size_t)64 * HDIM / 8; s += N) {
    int row = (int)(s >> 7), seg = (int)(s & 127) << 3;
    const float* src = (row < 32) ? (mw + (size_t)row * HDIM + seg)
                                  : (sw + (size_t)(row - 32) * HDIM + seg);
    cvt8(src, Wms + (size_t)row * HDIM + seg);
  }
  for (size_t s = g; s < 1536; s += N) {
    int pr = permRow((int)s);
    bi0[s] = bih0[pr]; bh0[s] = bhh0[pr];
    bi1[s] = bih1[pr]; bh1[s] = bhh1[pr];
  }
}

// ---------------- persistent cooperative mega-kernel ----------------
// Grid 512 = 2 blocks/CU. xcd = blockIdx&7 (HW round-robin). Roles are
// nb-SLICED per XCD so each XCD's L2 working set fits 4 MiB:
//   XCD0: GRU1 nb%3==0 (48 tiles, Wslice 1.2MB)   XCD1/2: nb%3==1/2 (40 each)
//   XCD3: GRU0 nb even (64)                       XCD4: GRU0 nb odd (64)
//   XCD5: D2 nb0-3 (32) + mean/std (8)
//   XCD6: D2 nb4-7 (32) + D1 nb0 (8)              XCD7: D1 nb1-7 (56)
// fp32 GRU h-state lives in 16 VGPRs per thread (block identity persists).
// Cross-XCD activation visibility: grid.sync() agent-scope release/acquire.
__global__ __launch_bounds__(256, 2) void mega_kernel(
    const float* __restrict__ y,
    const float* db1, const float* db2, const float* mbias, const float* sbias,
    char* __restrict__ ws)
{
  __shared__ short lds[2 * LDS_BUF];
  const int tid = threadIdx.x;
  const int xcd = blockIdx.x & 7;
  const int slot = blockIdx.x >> 3;

  // static role decode (0=GRU1, 1=GRU0, 2=D2, 3=D1, 4=MS, -1=idle)
  int role = -1, mb = 0, nb = 0;
  if (xcd < 3) {
    const int cnt = (xcd == 0) ? 6 : 5;
    if (slot < cnt * 8) { role = 0; nb = 3 * (slot >> 3) + xcd; mb = slot & 7; }
  } else if (xcd == 3) { role = 1; nb = 2 * (slot >> 3);     mb = slot & 7; }
  else if (xcd == 4)   { role = 1; nb = 2 * (slot >> 3) + 1; mb = slot & 7; }
  else if (xcd == 5) {
    if (slot < 32)      { role = 2; nb = slot >> 3; mb = slot & 7; }
    else if (slot < 40) { role = 4; mb = slot - 32; }
  } else if (xcd == 6) {
    if (slot < 32)      { role = 2; nb = 4 + (slot >> 3); mb = slot & 7; }
    else if (slot < 40) { role = 3; nb = 0; mb = slot - 32; }
  } else {
    if (slot < 56)      { role = 3; nb = 1 + (slot >> 3); mb = slot & 7; }
  }

  short* hA16 = (short*)(ws + OFF_HA16);
  short* hB16 = (short*)(ws + OFF_HB16);
  short* d10 = (short*)(ws + OFF_D1);
  short* d20 = (short*)(ws + OFF_D2);
  const short* y16 = (const short*)(ws + OFF_Y16);
  const short* Wg0i = (const short*)(ws + OFF_WG0I);
  const short* Wg0h = (const short*)(ws + OFF_WG0H);
  const short* Wg1i = (const short*)(ws + OFF_WG1I);
  const short* Wg1h = (const short*)(ws + OFF_WG1H);
  const short* Wd1  = (const short*)(ws + OFF_WD1);
  const short* Wd2  = (const short*)(ws + OFF_WD2);
  const short* Wms  = (const short*)(ws + OFF_WMS);
  const float* bi0  = (const float*)(ws + OFF_BI0);
  const float* bh0  = (const float*)(ws + OFF_BH0);
  const float* bi1  = (const float*)(ws + OFF_BI1);
  const float* bh1  = (const float*)(ws + OFF_BH1);
  float* nllp = (float*)(ws + OFF_NLL);

  float hreg[16];
#pragma unroll
  for (int i = 0; i < 16; ++i) hreg[i] = 0.f;

  cg::grid_group grid = cg::this_grid();

  for (int p = 0; p < 259; ++p) {
    const int cur = p & 1, prv = cur ^ 1;
    short* hA16c = hA16 + (size_t)cur * BB * RDIM;
    short* hA16p = hA16 + (size_t)prv * BB * RDIM;
    short* hB16c = hB16 + (size_t)cur * BB * RDIM;
    short* hB16p = hB16 + (size_t)prv * BB * RDIM;
    short* d1c = d10 + (size_t)cur * BB * HDIM;
    short* d1p = d10 + (size_t)prv * BB * HDIM;
    short* d2c = d20 + (size_t)cur * BB * HDIM;
    short* d2p = d20 + (size_t)prv * BB * HDIM;

    if (role == 0) {                 // GRU1 -> h1_{p-1}
      if (p >= 1 && p <= 255)
        gru_tile<false, true>(mb, nb,
                              hA16p, RDIM, Wg1i + (size_t)nb * 96 * RDIM,
                              hB16p, Wg1h + (size_t)nb * 96 * RDIM,
                              bi1, bh1, nullptr, nullptr, hreg, hB16c, lds, tid);
    } else if (role == 1) {          // GRU0 -> h0_p
      if (p <= 255)
        gru_tile<true, true>(mb, nb,
                             y16 + (size_t)p * BB * YDIM, YDIM, Wg0i + (size_t)nb * 96 * YDIM,
                             hA16p, Wg0h + (size_t)nb * 96 * RDIM,
                             bi0, bh0, nullptr, nullptr, hreg, hA16c, lds, tid);
    } else if (role == 2) {          // D2 for step p-2
      if (p >= 2 && p <= 257)
        dec_tile(mb, nb, d1p, HDIM, HDIM, Wd2 + (size_t)nb * 128 * HDIM,
                 db2, d2c, lds, tid);
    } else if (role == 3) {          // D1 for step p-1
      if (p >= 1 && p <= 256)
        dec_tile(mb, nb, hB16p, RDIM, RDIM, Wd1 + (size_t)nb * 128 * RDIM,
                 db1, d1c, lds, tid);
    } else if (role == 4) {          // mean/std + nll for step p-3
      if (p >= 3 && p <= 258)
        ms_tile(mb, p - 3, d2p, Wms, mbias, sbias, y, nllp, lds, tid);
    }
    grid.sync();
  }
}

// ---------------- fallback: one pipeline phase (r0 mapping, 392 blocks) ----------------
__global__ __launch_bounds__(256, 2) void phase_kernel(
    int p, const float* __restrict__ y,
    const float* db1, const float* db2, const float* mbias, const float* sbias,
    char* __restrict__ ws)
{
  __shared__ short lds[2 * LDS_BUF];
  const int tid = threadIdx.x;
  const int t = blockIdx.x;
  const int cur = p & 1, prv = cur ^ 1;

  float* hAf = (float*)(ws + OFF_HAF);
  float* hBf = (float*)(ws + OFF_HBF);
  short* hA16 = (short*)(ws + OFF_HA16);
  short* hB16 = (short*)(ws + OFF_HB16);
  short* d10 = (short*)(ws + OFF_D1);
  short* d20 = (short*)(ws + OFF_D2);
  const short* y16 = (const short*)(ws + OFF_Y16);

  float* hAfc = hAf + (size_t)cur * BB * RDIM;
  float* hAfp = hAf + (size_t)prv * BB * RDIM;
  float* hBfc = hBf + (size_t)cur * BB * RDIM;
  float* hBfp = hBf + (size_t)prv * BB * RDIM;
  short* hA16c = hA16 + (size_t)cur * BB * RDIM;
  short* hA16p = hA16 + (size_t)prv * BB * RDIM;
  short* hB16c = hB16 + (size_t)cur * BB * RDIM;
  short* hB16p = hB16 + (size_t)prv * BB * RDIM;
  short* d1c = d10 + (size_t)cur * BB * HDIM;
  short* d1p = d10 + (size_t)prv * BB * HDIM;
  short* d2c = d20 + (size_t)cur * BB * HDIM;
  short* d2p = d20 + (size_t)prv * BB * HDIM;

  const short* Wg0i = (const short*)(ws + OFF_WG0I);
  const short* Wg0h = (const short*)(ws + OFF_WG0H);
  const short* Wg1i = (const short*)(ws + OFF_WG1I);
  const short* Wg1h = (const short*)(ws + OFF_WG1H);
  const short* Wd1  = (const short*)(ws + OFF_WD1);
  const short* Wd2  = (const short*)(ws + OFF_WD2);
  const short* Wms  = (const short*)(ws + OFF_WMS);
  const float* bi0  = (const float*)(ws + OFF_BI0);
  const float* bh0  = (const float*)(ws + OFF_BH0);
  const float* bi1  = (const float*)(ws + OFF_BI1);
  const float* bh1  = (const float*)(ws + OFF_BH1);
  float* nllp = (float*)(ws + OFF_NLL);

  if (t < 128) {                    // GRU1 -> h1_{p-1}
    if (p >= 1 && p <= 255) {
      int mb = t >> 4, nb = t & 15;
      gru_tile<false, false>(mb, nb,
                             hA16p, RDIM, Wg1i + (size_t)nb * 96 * RDIM,
                             hB16p, Wg1h + (size_t)nb * 96 * RDIM,
                             bi1, bh1, hBfp, hBfc, nullptr, hB16c, lds, tid);
    }
  } else if (t < 192) {             // D2 for step p-2
    if (p >= 2 && p <= 257) {
      int q = t - 128, mb = q >> 3, nb = q & 7;
      dec_tile(mb, nb, d1p, HDIM, HDIM, Wd2 + (size_t)nb * 128 * HDIM,
               db2, d2c, lds, tid);
    }
  } else if (t < 200) {             // mean/std + nll for step p-3
    if (p >= 3 && p <= 258) {
      ms_tile(t - 192, p - 3, d2p, Wms, mbias, sbias, y, nllp, lds, tid);
    }
  } else if (t < 328) {             // GRU0 -> h0_p
    if (p <= 255) {
      int q = t - 200, mb = q >> 4, nb = q & 15;
      gru_tile<true, false>(mb, nb,
                            y16 + (size_t)p * BB * YDIM, YDIM, Wg0i + (size_t)nb * 96 * YDIM,
                            hA16p, Wg0h + (size_t)nb * 96 * RDIM,
                            bi0, bh0, hAfp, hAfc, nullptr, hA16c, lds, tid);
    }
  } else {                          // D1 for step p-1
    if (p >= 1 && p <= 256) {
      int q = t - 328, mb = q >> 3, nb = q & 7;
      dec_tile(mb, nb, hB16p, RDIM, RDIM, Wd1 + (size_t)nb * 128 * RDIM,
               db1, d1c, lds, tid);
    }
  }
}

__global__ void finish_kernel(float* out, const char* ws)
{
  if (threadIdx.x == 0 && blockIdx.x == 0)
    out[0] = *(const float*)(ws + OFF_NLL);
}

extern "C" void kernel_launch(void* const* d_in, const int* in_sizes, int n_in,
                              void* d_out, int out_size, void* d_ws, size_t ws_size,
                              hipStream_t stream) {
  (void)in_sizes; (void)n_in; (void)out_size; (void)ws_size;
  const float* y    = (const float*)d_in[0];
  const float* dw1  = (const float*)d_in[1];
  const float* db1  = (const float*)d_in[2];
  const float* dw2  = (const float*)d_in[3];
  const float* db2  = (const float*)d_in[4];
  const float* mw   = (const float*)d_in[5];
  const float* mbias= (const float*)d_in[6];
  const float* sw   = (const float*)d_in[7];
  const float* sbias= (const float*)d_in[8];
  const float* wih0 = (const float*)d_in[9];
  const float* whh0 = (const float*)d_in[10];
  const float* bih0 = (const float*)d_in[11];
  const float* bhh0 = (const float*)d_in[12];
  const float* wih1 = (const float*)d_in[13];
  const float* whh1 = (const float*)d_in[14];
  const float* bih1 = (const float*)d_in[15];
  const float* bhh1 = (const float*)d_in[16];
  char* ws = (char*)d_ws;
  float* out = (float*)d_out;

  prepack_kernel<<<256, 256, 0, stream>>>(y, dw1, dw2, mw, sw,
                                          wih0, whh0, bih0, bhh0,
                                          wih1, whh1, bih1, bhh1, ws);

  void* kargs[] = { (void*)&y, (void*)&db1, (void*)&db2,
                    (void*)&mbias, (void*)&sbias, (void*)&ws };
  hipError_t e = hipLaunchCooperativeKernel((void*)mega_kernel,
                                            dim3(512), dim3(256),
                                            kargs, 0, stream);
  if (e != hipSuccess) {
    (void)hipGetLastError();        // clear; fall back to launch-per-phase
    for (int p = 0; p < 259; ++p)
      phase_kernel<<<392, 256, 0, stream>>>(p, y, db1, db2, mbias, sbias, ws);
  }
  finish_kernel<<<1, 1, 0, stream>>>(out, ws);
}

// Round 3
// 6920.593 us; speedup vs baseline: 2.8710x; 2.8710x over previous
//
#include <hip/hip_runtime.h>
#include <math.h>

#define TT   256
#define BB   1024
#define YDIM 32
#define HDIM 1024
#define RDIM 512
#define CH   32      // decode chunk: timesteps per chunk

typedef __attribute__((ext_vector_type(8))) short frag8;
typedef __attribute__((ext_vector_type(4))) float f32x4;

#define LDS_BUF 16384  // shorts per double-buffer half: (128 A rows + 128 B rows) x 64

// ---------------- workspace layout (bytes) ----------------
#define OFF_NLL   ((size_t)0)
#define OFF_HAF   ((size_t)4096)                     // fp32 h0 x2 (state)
#define SZ_HF     ((size_t)BB*RDIM*4)
#define OFF_HBF   (OFF_HAF + 2*SZ_HF)                // fp32 h1 x2
#define OFF_HA16  (OFF_HBF + 2*SZ_HF)                // bf16 h0 x2 (GEMM operand copy)
#define SZ_H16    ((size_t)BB*RDIM*2)
#define OFF_HB16  (OFF_HA16 + 2*SZ_H16)              // bf16 h1 x2 (fallback path only)
#define OFF_D1    (OFF_HB16 + 2*SZ_H16)              // bf16 d1 x2 (fallback path only)
#define SZ_DBUF   ((size_t)BB*HDIM*2)
#define OFF_D2    (OFF_D1 + 2*SZ_DBUF)               // bf16 d2 x2 (fallback path only)
#define OFF_Y16   (OFF_D2 + 2*SZ_DBUF)               // bf16 y [T,B,32]
#define OFF_WG0I  (OFF_Y16 + (size_t)TT*BB*YDIM*2)
#define OFF_WG0H  (OFF_WG0I + (size_t)1536*YDIM*2)
#define OFF_WG1I  (OFF_WG0H + (size_t)1536*RDIM*2)
#define OFF_WG1H  (OFF_WG1I + (size_t)1536*RDIM*2)
#define OFF_WD1   (OFF_WG1H + (size_t)1536*RDIM*2)
#define OFF_WD2   (OFF_WD1 + (size_t)HDIM*RDIM*2)
#define OFF_WMS   (OFF_WD2 + (size_t)HDIM*HDIM*2)
#define OFF_BI0   (OFF_WMS + (size_t)64*HDIM*2)
#define OFF_BH0   (OFF_BI0 + 1536*4)
#define OFF_BI1   (OFF_BH0 + 1536*4)
#define OFF_BH1   (OFF_BI1 + 1536*4)
// ---- big-workspace extension (batched-decode path) ----
#define OFF_H1ALL (OFF_BH1 + 4096)                   // bf16 h1 archive [256][B][R]; entry t = h1[t-1]
#define SZ_H1ALL  ((size_t)TT*BB*RDIM*2)
#define OFF_D1CH  (OFF_H1ALL + SZ_H1ALL)             // bf16 d1 chunk [CH*B][H]
#define SZ_CHB    ((size_t)CH*BB*HDIM*2)
#define OFF_D2CH  (OFF_D1CH + SZ_CHB)                // bf16 d2 chunk
#define OFF_END   (OFF_D2CH + SZ_CHB)

__device__ __forceinline__ short f2bf(float f) {
  union { float f; unsigned u; } v; v.f = f;
  unsigned r = (v.u + 0x7fffu + ((v.u >> 16) & 1u)) >> 16;
  return (short)r;
}
__device__ __forceinline__ void cvt8(const float* s, short* d) {
  float4 a = *(const float4*)s;
  float4 b = *(const float4*)(s + 4);
  frag8 v;
  v[0]=f2bf(a.x); v[1]=f2bf(a.y); v[2]=f2bf(a.z); v[3]=f2bf(a.w);
  v[4]=f2bf(b.x); v[5]=f2bf(b.y); v[6]=f2bf(b.z); v[7]=f2bf(b.w);
  *(frag8*)d = v;
}
// gate-interleaved row permutation: packed row n = q*48 + g*16 + u  <->  src row g*512 + q*16 + u
__device__ __forceinline__ int permRow(int n) {
  int q = n / 48, r = n - 48 * q, g = r >> 4, u = r & 15;
  return g * 512 + q * 16 + u;
}
__device__ __forceinline__ float sigf(float x) { return 1.0f / (1.0f + expf(-x)); }

// async 16B global -> LDS (dest = uniform base + lane*16)
__device__ __forceinline__ void gload16(const short* g, short* l) {
  __builtin_amdgcn_global_load_lds(
      (const __attribute__((address_space(1))) void*)g,
      (__attribute__((address_space(3))) void*)l, 16, 0, 0);
}

// ---------------- double-buffered MFMA K-loop, 64-wide chunks ----------------
template<int MF, int NF>
__device__ __forceinline__ void kloop64(
    const short* __restrict__ A, int lda, int m0,
    const short* __restrict__ B, int ldb, int nrowsB, int K,
    int wm, int wn, short* lds, f32x4 (*acc)[NF], int tid)
{
  const int l = tid & 63, w = tid >> 6, u = l & 15, quad = l >> 4;
  const int nk = K >> 6;
  const int bunits = nrowsB << 3;

  auto stage = [&](int kc, int buf) {
    short* base = lds + buf * LDS_BUF;
    const int k0 = kc << 6;
    for (int c = (w << 6); c < 1024; c += 256) {
      int p = c + l, r = p >> 3, q = (p & 7) ^ (r & 7);
      gload16(A + (size_t)(m0 + r) * lda + k0 + (q << 3), base + (c << 3));
    }
    short* bb = base + 8192;
    for (int c = (w << 6); c < bunits; c += 256) {
      int p = c + l, r = p >> 3, q = (p & 7) ^ (r & 7);
      gload16(B + (size_t)r * ldb + k0 + (q << 3), bb + (c << 3));
    }
  };

  stage(0, 0);
  __syncthreads();
  for (int kc = 0; kc < nk; ++kc) {
    if (kc + 1 < nk) stage(kc + 1, (kc + 1) & 1);   // overlaps compute below
    const short* base = lds + (kc & 1) * LDS_BUF;
#pragma unroll
    for (int kk2 = 0; kk2 < 2; ++kk2) {
      const int q = (kk2 << 2) + quad;
      const int aoff = (q ^ (u & 7)) << 3;
      frag8 a[MF], b[NF];
#pragma unroll
      for (int i = 0; i < MF; ++i)
        a[i] = *(const frag8*)(base + ((wm + (i << 4) + u) << 6) + aoff);
#pragma unroll
      for (int f = 0; f < NF; ++f)
        b[f] = *(const frag8*)(base + 8192 + ((wn + (f << 4) + u) << 6) + aoff);
#pragma unroll
      for (int i = 0; i < MF; ++i)
#pragma unroll
        for (int f = 0; f < NF; ++f)
          acc[i][f] = __builtin_amdgcn_mfma_f32_16x16x32_bf16(a[i], b[f], acc[i][f], 0, 0, 0);
    }
    __syncthreads();  // drains stage(kc+1) loads (vmcnt 0) + guards buffer reuse
  }
}

// single 32-wide chunk (GRU layer0 gi, K=32)
template<int MF, int NF>
__device__ __forceinline__ void kloop32(
    const short* __restrict__ A, int lda, int m0,
    const short* __restrict__ B, int nrowsB,
    int wm, int wn, short* lds, f32x4 (*acc)[NF], int tid)
{
  const int l = tid & 63, w = tid >> 6, u = l & 15, quad = l >> 4;
  short* base = lds;
  for (int c = (w << 6); c < 512; c += 256) {
    int p = c + l, r = p >> 2, q = (p & 3) ^ (r & 3);
    gload16(A + (size_t)(m0 + r) * lda + (q << 3), base + (c << 3));
  }
  short* bb = base + 4096;
  const int bunits = nrowsB << 2;
  for (int c = (w << 6); c < bunits; c += 256) {
    int p = c + l, r = p >> 2, q = (p & 3) ^ (r & 3);
    gload16(B + (size_t)r * 32 + (q << 3), bb + (c << 3));
  }
  __syncthreads();
  const int aoff = (quad ^ (u & 3)) << 3;
  frag8 a[MF], b[NF];
#pragma unroll
  for (int i = 0; i < MF; ++i)
    a[i] = *(const frag8*)(base + ((wm + (i << 4) + u) << 5) + aoff);
#pragma unroll
  for (int f = 0; f < NF; ++f)
    b[f] = *(const frag8*)(base + 4096 + ((wn + (f << 4) + u) << 5) + aoff);
#pragma unroll
  for (int i = 0; i < MF; ++i)
#pragma unroll
    for (int f = 0; f < NF; ++f)
      acc[i][f] = __builtin_amdgcn_mfma_f32_16x16x32_bf16(a[i], b[f], acc[i][f], 0, 0, 0);
  __syncthreads();
}

// ---------------- GRU tile ----------------
template<bool GI32>
__device__ void gru_tile(int mb, int nb,
                         const short* Ax, int ldx, const short* Wgi,
                         const short* Ah, const short* Wgh,
                         const float* bi, const float* bh,
                         const float* hold, float* hout, short* h16out,
                         short* lds, int tid)
{
  f32x4 zero = {0.f, 0.f, 0.f, 0.f};
  f32x4 gi[4][3], gh[4][3];
#pragma unroll
  for (int i = 0; i < 4; ++i)
#pragma unroll
    for (int f = 0; f < 3; ++f) { gi[i][f] = zero; gh[i][f] = zero; }
  const int w = tid >> 6, l = tid & 63, u = l & 15, quad = l >> 4;
  const int wm = (w & 1) * 64, wn = (w >> 1) * 48;
  if (GI32)
    kloop32<4, 3>(Ax, ldx, mb * 128, Wgi, 96, wm, wn, lds, gi, tid);
  else
    kloop64<4, 3>(Ax, ldx, mb * 128, Wgi, RDIM, 96, RDIM, wm, wn, lds, gi, tid);
  kloop64<4, 3>(Ah, RDIM, mb * 128, Wgh, RDIM, 96, RDIM, wm, wn, lds, gh, tid);

  const int np = nb * 96 + (w >> 1) * 48 + u;
  const float bir = bi[np], biz = bi[np + 16], bin = bi[np + 32];
  const float bhr = bh[np], bhz = bh[np + 16], bhn = bh[np + 32];
  const int unit = nb * 32 + (w >> 1) * 16 + u;
#pragma unroll
  for (int i = 0; i < 4; ++i)
#pragma unroll
    for (int j = 0; j < 4; ++j) {
      int row = mb * 128 + wm + 16 * i + quad * 4 + j;
      float r = sigf((gi[i][0][j] + bir) + (gh[i][0][j] + bhr));
      float z = sigf((gi[i][1][j] + biz) + (gh[i][1][j] + bhz));
      float n = tanhf((gi[i][2][j] + bin) + r * (gh[i][2][j] + bhn));
      float ho = hold[(size_t)row * RDIM + unit];
      float hn = (1.f - z) * n + z * ho;
      hout[(size_t)row * RDIM + unit] = hn;
      h16out[(size_t)row * RDIM + unit] = f2bf(hn);
    }
}

// ---------------- decoder Linear+ReLU tile (128x128) ----------------
__device__ void dec_tile(int mb, int nb, const short* A, int lda, int K,
                         const short* W, const float* bias, short* outp,
                         short* lds, int tid)
{
  f32x4 zero = {0.f, 0.f, 0.f, 0.f};
  f32x4 acc[4][4];
#pragma unroll
  for (int i = 0; i < 4; ++i)
#pragma unroll
    for (int f = 0; f < 4; ++f) acc[i][f] = zero;
  const int w = tid >> 6, l = tid & 63, u = l & 15, quad = l >> 4;
  const int wm = (w & 1) * 64, wn = (w >> 1) * 64;
  kloop64<4, 4>(A, lda, mb * 128, W, K, 128, K, wm, wn, lds, acc, tid);
  const int colb = nb * 128 + wn + u;
  float bv[4];
#pragma unroll
  for (int f = 0; f < 4; ++f) bv[f] = bias[colb + 16 * f];
#pragma unroll
  for (int i = 0; i < 4; ++i)
#pragma unroll
    for (int f = 0; f < 4; ++f)
#pragma unroll
      for (int j = 0; j < 4; ++j) {
        int row = mb * 128 + wm + 16 * i + quad * 4 + j;
        float v = acc[i][f][j] + bv[f];
        if (v < 0.f) v = 0.f;
        outp[(size_t)row * HDIM + colb + 16 * f] = f2bf(v);
      }
}

// ---------------- mean/std + gaussian NLL tile (rows = flattened (t,b)) ----------------
__device__ void ms_tile(int mb, const short* d2p, const short* Wms,
                        const float* mbias, const float* sbias, const float* ybase,
                        float* nll, short* lds, int tid)
{
  f32x4 zero = {0.f, 0.f, 0.f, 0.f};
  f32x4 acc[2][4];
#pragma unroll
  for (int i = 0; i < 2; ++i)
#pragma unroll
    for (int f = 0; f < 4; ++f) acc[i][f] = zero;
  const int w = tid >> 6, l = tid & 63, u = l & 15, quad = l >> 4;
  kloop64<2, 4>(d2p, HDIM, mb * 128, Wms, HDIM, 64, HDIM, w * 32, 0, lds, acc, tid);
  float lsum = 0.f;
#pragma unroll
  for (int i = 0; i < 2; ++i)
#pragma unroll
    for (int j = 0; j < 4; ++j) {
      int row = mb * 128 + w * 32 + 16 * i + quad * 4 + j;
      const float* yr = ybase + (size_t)row * YDIM;
#pragma unroll
      for (int f = 0; f < 2; ++f) {
        int c = 16 * f + u;
        float m  = acc[i][f][j] + mbias[c];
        float sp = acc[i][f + 2][j] + sbias[c];
        float sg = (sp > 20.f) ? sp : log1pf(expf(sp));
        float dv = (yr[c] - m) / sg;
        lsum += dv * dv + 2.f * logf(sg) + 1.8378770664093453f;
      }
    }
  lsum *= 0.5f;
#pragma unroll
  for (int o = 32; o; o >>= 1) lsum += __shfl_xor(lsum, o);
  if (l == 0) atomicAdd(nll, lsum);
}

// ---------------- prepack ----------------
__global__ __launch_bounds__(256) void prepack_kernel(
    const float* y, const float* dw1, const float* dw2,
    const float* mw, const float* sw,
    const float* wih0, const float* whh0, const float* bih0, const float* bhh0,
    const float* wih1, const float* whh1, const float* bih1, const float* bhh1,
    char* __restrict__ ws, int big)
{
  const size_t g = (size_t)blockIdx.x * 256 + threadIdx.x;
  const size_t N = (size_t)gridDim.x * 256;
  float4 z4 = {0.f, 0.f, 0.f, 0.f};
  float4* hz = (float4*)(ws + OFF_HAF);
  for (size_t i = g; i < (size_t)4 * BB * RDIM / 4; i += N) hz[i] = z4;
  int4 zi = {0, 0, 0, 0};
  int4* h16z = (int4*)(ws + OFF_HA16);
  for (size_t i = g; i < (size_t)4 * BB * RDIM / 8; i += N) h16z[i] = zi;
  if (big) {   // zero H1ALL[0] (= h1 state before step 0)
    int4* h1z = (int4*)(ws + OFF_H1ALL);
    for (size_t i = g; i < (size_t)BB * RDIM / 8; i += N) h1z[i] = zi;
  }
  if (g == 0) *(float*)(ws + OFF_NLL) = 0.f;

  short* y16  = (short*)(ws + OFF_Y16);
  short* Wg0i = (short*)(ws + OFF_WG0I);
  short* Wg0h = (short*)(ws + OFF_WG0H);
  short* Wg1i = (short*)(ws + OFF_WG1I);
  short* Wg1h = (short*)(ws + OFF_WG1H);
  short* Wd1  = (short*)(ws + OFF_WD1);
  short* Wd2  = (short*)(ws + OFF_WD2);
  short* Wms  = (short*)(ws + OFF_WMS);
  float* bi0  = (float*)(ws + OFF_BI0);
  float* bh0  = (float*)(ws + OFF_BH0);
  float* bi1  = (float*)(ws + OFF_BI1);
  float* bh1  = (float*)(ws + OFF_BH1);

  for (size_t s = g; s < (size_t)TT * BB * YDIM / 8; s += N)
    cvt8(y + s * 8, y16 + s * 8);
  for (size_t s = g; s < (size_t)1536 * RDIM / 8; s += N) {
    int row = (int)(s >> 6), seg = (int)(s & 63) << 3;
    int pr = permRow(row);
    cvt8(whh0 + (size_t)pr * RDIM + seg, Wg0h + (size_t)row * RDIM + seg);
    cvt8(wih1 + (size_t)pr * RDIM + seg, Wg1i + (size_t)row * RDIM + seg);
    cvt8(whh1 + (size_t)pr * RDIM + seg, Wg1h + (size_t)row * RDIM + seg);
  }
  for (size_t s = g; s < (size_t)1536 * YDIM / 8; s += N) {
    int row = (int)(s >> 2), seg = (int)(s & 3) << 3;
    cvt8(wih0 + (size_t)permRow(row) * YDIM + seg, Wg0i + (size_t)row * YDIM + seg);
  }
  for (size_t s = g; s < (size_t)HDIM * RDIM / 8; s += N)
    cvt8(dw1 + s * 8, Wd1 + s * 8);
  for (size_t s = g; s < (size_t)HDIM * HDIM / 8; s += N)
    cvt8(dw2 + s * 8, Wd2 + s * 8);
  for (size_t s = g; s < (size_t)64 * HDIM / 8; s += N) {
    int row = (int)(s >> 7), seg = (int)(s & 127) << 3;
    const float* src = (row < 32) ? (mw + (size_t)row * HDIM + seg)
                                  : (sw + (size_t)(row - 32) * HDIM + seg);
    cvt8(src, Wms + (size_t)row * HDIM + seg);
  }
  for (size_t s = g; s < 1536; s += N) {
    int pr = permRow((int)s);
    bi0[s] = bih0[pr]; bh0[s] = bhh0[pr];
    bi1[s] = bih1[pr]; bh1[s] = bhh1[pr];
  }
}

// ---------------- recurrence step: GRU0[p] || GRU1[p-1] ----------------
// Grid 256 (1 block/CU). xcd = blockIdx&7 (HW round-robin). nb-sliced pinning:
//   XCD 0-3: GRU1, nb = xcd*4 + (slot&3)  (W slice 0.78MB + A 2MB + fp32 1MB -> L2)
//   XCD 4-7: GRU0, nb = (xcd-4)*4 + (slot&3)
// h1 archive: entry t holds h1[t-1]; GRU1 at t=p-1 reads entry p-1, writes entry p.
__global__ __launch_bounds__(256, 2) void recur_kernel(int p, char* __restrict__ ws)
{
  __shared__ short lds[2 * LDS_BUF];
  const int tid = threadIdx.x;
  const int xcd = blockIdx.x & 7;
  const int slot = blockIdx.x >> 3;
  const int cur = p & 1, prv = cur ^ 1;

  float* hAf = (float*)(ws + OFF_HAF);
  float* hBf = (float*)(ws + OFF_HBF);
  short* hA16 = (short*)(ws + OFF_HA16);
  short* h1all = (short*)(ws + OFF_H1ALL);
  const short* y16 = (const short*)(ws + OFF_Y16);
  const short* Wg0i = (const short*)(ws + OFF_WG0I);
  const short* Wg0h = (const short*)(ws + OFF_WG0H);
  const short* Wg1i = (const short*)(ws + OFF_WG1I);
  const short* Wg1h = (const short*)(ws + OFF_WG1H);
  const float* bi0  = (const float*)(ws + OFF_BI0);
  const float* bh0  = (const float*)(ws + OFF_BH0);
  const float* bi1  = (const float*)(ws + OFF_BI1);
  const float* bh1  = (const float*)(ws + OFF_BH1);

  const int nb = (xcd & 3) * 4 + (slot & 3);
  const int mb = slot >> 2;

  if (xcd < 4) {                    // GRU1 at t = p-1
    if (p >= 1) {
      gru_tile<false>(mb, nb,
                      hA16 + (size_t)prv * BB * RDIM, RDIM, Wg1i + (size_t)nb * 96 * RDIM,
                      h1all + (size_t)(p - 1) * BB * RDIM, Wg1h + (size_t)nb * 96 * RDIM,
                      bi1, bh1,
                      hBf + (size_t)prv * BB * RDIM, hBf + (size_t)cur * BB * RDIM,
                      h1all + (size_t)p * BB * RDIM, lds, tid);
    }
  } else {                          // GRU0 at t = p
    if (p <= 254) {
      gru_tile<true>(mb, nb,
                     y16 + (size_t)p * BB * YDIM, YDIM, Wg0i + (size_t)nb * 96 * YDIM,
                     hA16 + (size_t)prv * BB * RDIM, Wg0h + (size_t)nb * 96 * RDIM,
                     bi0, bh0,
                     hAf + (size_t)prv * BB * RDIM, hAf + (size_t)cur * BB * RDIM,
                     hA16 + (size_t)cur * BB * RDIM, lds, tid);
    }
  }
}

// ---------------- batched decode: D1 / D2 / ms over a 32-step chunk ----------------
// 2048 blocks; XCD x handles m-tiles [x*32, x*32+32) x all 8 nb -> W slice in L2,
// consecutive slots share the same m-tile so the A-tile gets L2 reuse across nb.
__global__ __launch_bounds__(256, 2) void d1_kernel(int c_, const float* db1, char* __restrict__ ws)
{
  __shared__ short lds[2 * LDS_BUF];
  const int tid = threadIdx.x;
  const int xcd = blockIdx.x & 7, slot = blockIdx.x >> 3;
  const int mt = xcd * 32 + (slot >> 3), nb = slot & 7;
  const short* A = (const short*)(ws + OFF_H1ALL) + (size_t)c_ * CH * BB * RDIM;
  const short* Wd1 = (const short*)(ws + OFF_WD1);
  short* d1ch = (short*)(ws + OFF_D1CH);
  dec_tile(mt, nb, A, RDIM, RDIM, Wd1 + (size_t)nb * 128 * RDIM, db1, d1ch, lds, tid);
}

__global__ __launch_bounds__(256, 2) void d2_kernel(int c_, const float* db2, char* __restrict__ ws)
{
  __shared__ short lds[2 * LDS_BUF];
  const int tid = threadIdx.x;
  const int xcd = blockIdx.x & 7, slot = blockIdx.x >> 3;
  const int mt = xcd * 32 + (slot >> 3), nb = slot & 7;
  const short* d1ch = (const short*)(ws + OFF_D1CH);
  const short* Wd2 = (const short*)(ws + OFF_WD2);
  short* d2ch = (short*)(ws + OFF_D2CH);
  dec_tile(mt, nb, d1ch, HDIM, HDIM, Wd2 + (size_t)nb * 128 * HDIM, db2, d2ch, lds, tid);
}

__global__ __launch_bounds__(256, 2) void msd_kernel(int c_, const float* mbias, const float* sbias,
                                                     const float* y, char* __restrict__ ws)
{
  __shared__ short lds[2 * LDS_BUF];
  const int tid = threadIdx.x;
  const int mb = (blockIdx.x & 7) * 32 + (blockIdx.x >> 3);
  const short* d2ch = (const short*)(ws + OFF_D2CH);
  const short* Wms = (const short*)(ws + OFF_WMS);
  float* nllp = (float*)(ws + OFF_NLL);
  ms_tile(mb, d2ch, Wms, mbias, sbias, y + (size_t)c_ * CH * BB * YDIM, nllp, lds, tid);
}

// ---------------- fallback: proven r0 pipeline phase (392 blocks) ----------------
__global__ __launch_bounds__(256, 2) void phase_kernel(
    int p, const float* __restrict__ y,
    const float* db1, const float* db2, const float* mbias, const float* sbias,
    char* __restrict__ ws)
{
  __shared__ short lds[2 * LDS_BUF];
  const int tid = threadIdx.x;
  const int t = blockIdx.x;
  const int cur = p & 1, prv = cur ^ 1;

  float* hAf = (float*)(ws + OFF_HAF);
  float* hBf = (float*)(ws + OFF_HBF);
  short* hA16 = (short*)(ws + OFF_HA16);
  short* hB16 = (short*)(ws + OFF_HB16);
  short* d10 = (short*)(ws + OFF_D1);
  short* d20 = (short*)(ws + OFF_D2);
  const short* y16 = (const short*)(ws + OFF_Y16);

  float* hAfc = hAf + (size_t)cur * BB * RDIM;
  float* hAfp = hAf + (size_t)prv * BB * RDIM;
  float* hBfc = hBf + (size_t)cur * BB * RDIM;
  float* hBfp = hBf + (size_t)prv * BB * RDIM;
  short* hA16c = hA16 + (size_t)cur * BB * RDIM;
  short* hA16p = hA16 + (size_t)prv * BB * RDIM;
  short* hB16c = hB16 + (size_t)cur * BB * RDIM;
  short* hB16p = hB16 + (size_t)prv * BB * RDIM;
  short* d1c = d10 + (size_t)cur * BB * HDIM;
  short* d1p = d10 + (size_t)prv * BB * HDIM;
  short* d2c = d20 + (size_t)cur * BB * HDIM;
  short* d2p = d20 + (size_t)prv * BB * HDIM;

  const short* Wg0i = (const short*)(ws + OFF_WG0I);
  const short* Wg0h = (const short*)(ws + OFF_WG0H);
  const short* Wg1i = (const short*)(ws + OFF_WG1I);
  const short* Wg1h = (const short*)(ws + OFF_WG1H);
  const short* Wd1  = (const short*)(ws + OFF_WD1);
  const short* Wd2  = (const short*)(ws + OFF_WD2);
  const short* Wms  = (const short*)(ws + OFF_WMS);
  const float* bi0  = (const float*)(ws + OFF_BI0);
  const float* bh0  = (const float*)(ws + OFF_BH0);
  const float* bi1  = (const float*)(ws + OFF_BI1);
  const float* bh1  = (const float*)(ws + OFF_BH1);
  float* nllp = (float*)(ws + OFF_NLL);

  if (t < 128) {                    // GRU1 -> h1_{p-1}
    if (p >= 1 && p <= 255) {
      int mb = t >> 4, nb = t & 15;
      gru_tile<false>(mb, nb,
                      hA16p, RDIM, Wg1i + (size_t)nb * 96 * RDIM,
                      hB16p, Wg1h + (size_t)nb * 96 * RDIM,
                      bi1, bh1, hBfp, hBfc, hB16c, lds, tid);
    }
  } else if (t < 192) {             // D2 for step p-2
    if (p >= 2 && p <= 257) {
      int q = t - 128, mb = q >> 3, nb = q & 7;
      dec_tile(mb, nb, d1p, HDIM, HDIM, Wd2 + (size_t)nb * 128 * HDIM,
               db2, d2c, lds, tid);
    }
  } else if (t < 200) {             // mean/std + nll for step p-3
    if (p >= 3 && p <= 258) {
      ms_tile(t - 192, d2p, Wms, mbias, sbias,
              y + (size_t)(p - 3) * BB * YDIM, nllp, lds, tid);
    }
  } else if (t < 328) {             // GRU0 -> h0_p
    if (p <= 255) {
      int q = t - 200, mb = q >> 4, nb = q & 15;
      gru_tile<true>(mb, nb,
                     y16 + (size_t)p * BB * YDIM, YDIM, Wg0i + (size_t)nb * 96 * YDIM,
                     hA16p, Wg0h + (size_t)nb * 96 * RDIM,
                     bi0, bh0, hAfp, hAfc, hA16c, lds, tid);
    }
  } else {                          // D1 for step p-1
    if (p >= 1 && p <= 256) {
      int q = t - 328, mb = q >> 3, nb = q & 7;
      dec_tile(mb, nb, hB16p, RDIM, RDIM, Wd1 + (size_t)nb * 128 * RDIM,
               db1, d1c, lds, tid);
    }
  }
}

__global__ void finish_kernel(float* out, const char* ws)
{
  if (threadIdx.x == 0 && blockIdx.x == 0)
    out[0] = *(const float*)(ws + OFF_NLL);
}

extern "C" void kernel_launch(void* const* d_in, const int* in_sizes, int n_in,
                              void* d_out, int out_size, void* d_ws, size_t ws_size,
                              hipStream_t stream) {
  (void)in_sizes; (void)n_in; (void)out_size;
  const float* y    = (const float*)d_in[0];
  const float* dw1  = (const float*)d_in[1];
  const float* db1  = (const float*)d_in[2];
  const float* dw2  = (const float*)d_in[3];
  const float* db2  = (const float*)d_in[4];
  const float* mw   = (const float*)d_in[5];
  const float* mbias= (const float*)d_in[6];
  const float* sw   = (const float*)d_in[7];
  const float* sbias= (const float*)d_in[8];
  const float* wih0 = (const float*)d_in[9];
  const float* whh0 = (const float*)d_in[10];
  const float* bih0 = (const float*)d_in[11];
  const float* bhh0 = (const float*)d_in[12];
  const float* wih1 = (const float*)d_in[13];
  const float* whh1 = (const float*)d_in[14];
  const float* bih1 = (const float*)d_in[15];
  const float* bhh1 = (const float*)d_in[16];
  char* ws = (char*)d_ws;
  float* out = (float*)d_out;

  const int big = (ws_size >= OFF_END) ? 1 : 0;

  prepack_kernel<<<256, 256, 0, stream>>>(y, dw1, dw2, mw, sw,
                                          wih0, whh0, bih0, bhh0,
                                          wih1, whh1, bih1, bhh1, ws, big);
  if (big) {
    // recurrence: 256 small pinned dispatches
    for (int p = 0; p < 256; ++p)
      recur_kernel<<<256, 256, 0, stream>>>(p, ws);
    // batched decode: 8 chunks x (D1, D2, ms)
    for (int c_ = 0; c_ < TT / CH; ++c_) {
      d1_kernel<<<2048, 256, 0, stream>>>(c_, db1, ws);
      d2_kernel<<<2048, 256, 0, stream>>>(c_, db2, ws);
      msd_kernel<<<256, 256, 0, stream>>>(c_, mbias, sbias, y, ws);
    }
  } else {
    for (int p = 0; p < 259; ++p)
      phase_kernel<<<392, 256, 0, stream>>>(p, y, db1, db2, mbias, sbias, ws);
  }
  finish_kernel<<<1, 1, 0, stream>>>(out, ws);
}

// Round 4
// 5370.360 us; speedup vs baseline: 3.6997x; 1.2887x over previous
//
#include <hip/hip_runtime.h>
#include <math.h>

#define TT   256
#define BB   1024
#define YDIM 32
#define HDIM 1024
#define RDIM 512

typedef __attribute__((ext_vector_type(8))) short frag8;
typedef __attribute__((ext_vector_type(4))) float f32x4;

#define LDS_BUF 16384  // shorts per double-buffer half: (128 A rows + 128 B rows) x 64

// ---------------- workspace layout (bytes) ----------------
#define OFF_NLL   ((size_t)0)
#define OFF_HAF   ((size_t)4096)                     // fp32 h0 x2 (state)
#define SZ_HF     ((size_t)BB*RDIM*4)
#define OFF_HBF   (OFF_HAF + 2*SZ_HF)                // fp32 h1 x2
#define OFF_HA16  (OFF_HBF + 2*SZ_HF)                // bf16 h0 x2 (GEMM operand copy)
#define SZ_H16    ((size_t)BB*RDIM*2)
#define OFF_HB16  (OFF_HA16 + 2*SZ_H16)              // bf16 h1 x2
#define OFF_D1    (OFF_HB16 + 2*SZ_H16)              // bf16 d1 x2
#define SZ_DBUF   ((size_t)BB*HDIM*2)
#define OFF_D2    (OFF_D1 + 2*SZ_DBUF)               // bf16 d2 x2
#define OFF_Y16   (OFF_D2 + 2*SZ_DBUF)               // bf16 y [T,B,32]
#define OFF_WG0I  (OFF_Y16 + (size_t)TT*BB*YDIM*2)
#define OFF_WG0H  (OFF_WG0I + (size_t)1536*YDIM*2)
#define OFF_WG1I  (OFF_WG0H + (size_t)1536*RDIM*2)
#define OFF_WG1H  (OFF_WG1I + (size_t)1536*RDIM*2)
#define OFF_WD1   (OFF_WG1H + (size_t)1536*RDIM*2)
#define OFF_WD2   (OFF_WD1 + (size_t)HDIM*RDIM*2)
#define OFF_WMS   (OFF_WD2 + (size_t)HDIM*HDIM*2)
#define OFF_BI0   (OFF_WMS + (size_t)64*HDIM*2)
#define OFF_BH0   (OFF_BI0 + 1536*4)
#define OFF_BI1   (OFF_BH0 + 1536*4)
#define OFF_BH1   (OFF_BI1 + 1536*4)

__device__ __forceinline__ short f2bf(float f) {
  union { float f; unsigned u; } v; v.f = f;
  unsigned r = (v.u + 0x7fffu + ((v.u >> 16) & 1u)) >> 16;
  return (short)r;
}
__device__ __forceinline__ void cvt8(const float* s, short* d) {
  float4 a = *(const float4*)s;
  float4 b = *(const float4*)(s + 4);
  frag8 v;
  v[0]=f2bf(a.x); v[1]=f2bf(a.y); v[2]=f2bf(a.z); v[3]=f2bf(a.w);
  v[4]=f2bf(b.x); v[5]=f2bf(b.y); v[6]=f2bf(b.z); v[7]=f2bf(b.w);
  *(frag8*)d = v;
}
// gate-interleaved row permutation: packed row n = q*48 + g*16 + u  <->  src row g*512 + q*16 + u
__device__ __forceinline__ int permRow(int n) {
  int q = n / 48, r = n - 48 * q, g = r >> 4, u = r & 15;
  return g * 512 + q * 16 + u;
}
__device__ __forceinline__ float sigf(float x) { return 1.0f / (1.0f + expf(-x)); }

// async 16B global -> LDS (dest = uniform base + lane*16)
__device__ __forceinline__ void gload16(const short* g, short* l) {
  __builtin_amdgcn_global_load_lds(
      (const __attribute__((address_space(1))) void*)g,
      (__attribute__((address_space(3))) void*)l, 16, 0, 0);
}

// counted vmcnt wait (literal immediates; "memory" keeps loads/reads ordered)
template<int N> __device__ __forceinline__ void waitv() {
  if constexpr (N == 0)      asm volatile("s_waitcnt vmcnt(0)" ::: "memory");
  else if constexpr (N == 6) asm volatile("s_waitcnt vmcnt(6)" ::: "memory");
  else if constexpr (N == 7) asm volatile("s_waitcnt vmcnt(7)" ::: "memory");
  else if constexpr (N == 8) asm volatile("s_waitcnt vmcnt(8)" ::: "memory");
  else                       asm volatile("s_waitcnt vmcnt(0)" ::: "memory");
}

// ---------------- double-buffered MFMA K-loop, 64-wide chunks ----------------
// A: bf16 [*, lda], 128 rows from m0. B: prepacked bf16 [NROWSB, ldb].
// LDS tile layout: 16B unit p = row*8 + (q ^ (row&7)), q = logical 8-elem segment.
//
// Counted-vmcnt pipeline (T4): per iteration we issue stage(kc+1) and then wait
// vmcnt(LPS) — draining only stage(kc), leaving stage(kc+1) in flight across the
// barrier. Successive stage latencies overlap 2-deep (T ~= L/2) instead of the
// full per-iteration round-trip the old __syncthreads() vmcnt(0) drain paid.
// LPS = loads/wave/stage = 4 (A) + NROWSB/32 (B); uniform across waves.
template<int MF, int NF, int NROWSB>
__device__ __forceinline__ void kloop64(
    const short* __restrict__ A, int lda, int m0,
    const short* __restrict__ B, int ldb, int K,
    int wm, int wn, short* lds, f32x4 (*acc)[NF], int tid)
{
  const int l = tid & 63, w = tid >> 6, u = l & 15, quad = l >> 4;
  const int nk = K >> 6;                 // always even (8 or 16)
  constexpr int BUNITS = NROWSB << 3;
  constexpr int LPS = 4 + NROWSB / 32;   // 96->7, 128->8, 64->6

  auto stage = [&](int kc, int buf) {
    short* base = lds + buf * LDS_BUF;
    const int k0 = kc << 6;
    for (int c = (w << 6); c < 1024; c += 256) {
      int p = c + l, r = p >> 3, q = (p & 7) ^ (r & 7);
      gload16(A + (size_t)(m0 + r) * lda + k0 + (q << 3), base + (c << 3));
    }
    short* bb = base + 8192;
    for (int c = (w << 6); c < BUNITS; c += 256) {
      int p = c + l, r = p >> 3, q = (p & 7) ^ (r & 7);
      gload16(B + (size_t)r * ldb + k0 + (q << 3), bb + (c << 3));
    }
  };

  stage(0, 0);
  for (int kc = 0; kc < nk; ++kc) {
    // read-guard: all waves finished ds_reads of buf[(kc+1)&1] (compute kc-1)
    asm volatile("s_waitcnt lgkmcnt(0)" ::: "memory");
    __builtin_amdgcn_s_barrier();
    if (kc + 1 < nk) {
      stage(kc + 1, (kc + 1) & 1);       // issue next; stays in flight past barrier
      waitv<LPS>();                      // only stage(kc) must have landed
    } else {
      waitv<0>();                        // last chunk: drain it
    }
    __builtin_amdgcn_s_barrier();        // stage(kc) visible to all waves
    asm volatile("" ::: "memory");       // no LDS read hoists above the barrier
    const short* base = lds + (kc & 1) * LDS_BUF;
#pragma unroll
    for (int kk2 = 0; kk2 < 2; ++kk2) {
      const int q = (kk2 << 2) + quad;
      const int aoff = (q ^ (u & 7)) << 3;
      frag8 a[MF], b[NF];
#pragma unroll
      for (int i = 0; i < MF; ++i)
        a[i] = *(const frag8*)(base + ((wm + (i << 4) + u) << 6) + aoff);
#pragma unroll
      for (int f = 0; f < NF; ++f)
        b[f] = *(const frag8*)(base + 8192 + ((wn + (f << 4) + u) << 6) + aoff);
#pragma unroll
      for (int i = 0; i < MF; ++i)
#pragma unroll
        for (int f = 0; f < NF; ++f)
          acc[i][f] = __builtin_amdgcn_mfma_f32_16x16x32_bf16(a[i], b[f], acc[i][f], 0, 0, 0);
    }
  }
  // exit note: nk is even, so the next kloop's stage(0, buf0) overwrites the
  // buffer whose readers were already barrier-guarded at iter nk-1's top.
}

// single 32-wide chunk (GRU layer0 gi, K=32)
template<int MF, int NF>
__device__ __forceinline__ void kloop32(
    const short* __restrict__ A, int lda, int m0,
    const short* __restrict__ B, int nrowsB,
    int wm, int wn, short* lds, f32x4 (*acc)[NF], int tid)
{
  const int l = tid & 63, w = tid >> 6, u = l & 15, quad = l >> 4;
  short* base = lds;
  for (int c = (w << 6); c < 512; c += 256) {
    int p = c + l, r = p >> 2, q = (p & 3) ^ (r & 3);
    gload16(A + (size_t)(m0 + r) * lda + (q << 3), base + (c << 3));
  }
  short* bb = base + 4096;
  const int bunits = nrowsB << 2;
  for (int c = (w << 6); c < bunits; c += 256) {
    int p = c + l, r = p >> 2, q = (p & 3) ^ (r & 3);
    gload16(B + (size_t)r * 32 + (q << 3), bb + (c << 3));
  }
  __syncthreads();
  const int aoff = (quad ^ (u & 3)) << 3;
  frag8 a[MF], b[NF];
#pragma unroll
  for (int i = 0; i < MF; ++i)
    a[i] = *(const frag8*)(base + ((wm + (i << 4) + u) << 5) + aoff);
#pragma unroll
  for (int f = 0; f < NF; ++f)
    b[f] = *(const frag8*)(base + 4096 + ((wn + (f << 4) + u) << 5) + aoff);
#pragma unroll
  for (int i = 0; i < MF; ++i)
#pragma unroll
    for (int f = 0; f < NF; ++f)
      acc[i][f] = __builtin_amdgcn_mfma_f32_16x16x32_bf16(a[i], b[f], acc[i][f], 0, 0, 0);
  __syncthreads();
}

// ---------------- GRU tile ----------------
template<bool GI32>
__device__ void gru_tile(int mb, int nb,
                         const short* Ax, int ldx, const short* Wgi,
                         const short* Ah, const short* Wgh,
                         const float* bi, const float* bh,
                         const float* hold, float* hout, short* h16out,
                         short* lds, int tid)
{
  f32x4 zero = {0.f, 0.f, 0.f, 0.f};
  f32x4 gi[4][3], gh[4][3];
#pragma unroll
  for (int i = 0; i < 4; ++i)
#pragma unroll
    for (int f = 0; f < 3; ++f) { gi[i][f] = zero; gh[i][f] = zero; }
  const int w = tid >> 6, l = tid & 63, u = l & 15, quad = l >> 4;
  const int wm = (w & 1) * 64, wn = (w >> 1) * 48;
  if (GI32)
    kloop32<4, 3>(Ax, ldx, mb * 128, Wgi, 96, wm, wn, lds, gi, tid);
  else
    kloop64<4, 3, 96>(Ax, ldx, mb * 128, Wgi, RDIM, RDIM, wm, wn, lds, gi, tid);
  kloop64<4, 3, 96>(Ah, RDIM, mb * 128, Wgh, RDIM, RDIM, wm, wn, lds, gh, tid);

  const int np = nb * 96 + (w >> 1) * 48 + u;
  const float bir = bi[np], biz = bi[np + 16], bin = bi[np + 32];
  const float bhr = bh[np], bhz = bh[np + 16], bhn = bh[np + 32];
  const int unit = nb * 32 + (w >> 1) * 16 + u;
#pragma unroll
  for (int i = 0; i < 4; ++i)
#pragma unroll
    for (int j = 0; j < 4; ++j) {
      int row = mb * 128 + wm + 16 * i + quad * 4 + j;
      float r = sigf((gi[i][0][j] + bir) + (gh[i][0][j] + bhr));
      float z = sigf((gi[i][1][j] + biz) + (gh[i][1][j] + bhz));
      float n = tanhf((gi[i][2][j] + bin) + r * (gh[i][2][j] + bhn));
      float ho = hold[(size_t)row * RDIM + unit];
      float hn = (1.f - z) * n + z * ho;
      hout[(size_t)row * RDIM + unit] = hn;
      h16out[(size_t)row * RDIM + unit] = f2bf(hn);
    }
}

// ---------------- decoder Linear+ReLU tile (128x128) ----------------
__device__ void dec_tile(int mb, int nb, const short* A, int lda, int K,
                         const short* W, const float* bias, short* outp,
                         short* lds, int tid)
{
  f32x4 zero = {0.f, 0.f, 0.f, 0.f};
  f32x4 acc[4][4];
#pragma unroll
  for (int i = 0; i < 4; ++i)
#pragma unroll
    for (int f = 0; f < 4; ++f) acc[i][f] = zero;
  const int w = tid >> 6, l = tid & 63, u = l & 15, quad = l >> 4;
  const int wm = (w & 1) * 64, wn = (w >> 1) * 64;
  kloop64<4, 4, 128>(A, lda, mb * 128, W, K, K, wm, wn, lds, acc, tid);
  const int colb = nb * 128 + wn + u;
  float bv[4];
#pragma unroll
  for (int f = 0; f < 4; ++f) bv[f] = bias[colb + 16 * f];
#pragma unroll
  for (int i = 0; i < 4; ++i)
#pragma unroll
    for (int f = 0; f < 4; ++f)
#pragma unroll
      for (int j = 0; j < 4; ++j) {
        int row = mb * 128 + wm + 16 * i + quad * 4 + j;
        float v = acc[i][f][j] + bv[f];
        if (v < 0.f) v = 0.f;
        outp[(size_t)row * HDIM + colb + 16 * f] = f2bf(v);
      }
}

// ---------------- mean/std + gaussian NLL tile ----------------
__device__ void ms_tile(int mb, int tstep, const short* d2p, const short* Wms,
                        const float* mbias, const float* sbias, const float* y,
                        float* nll, short* lds, int tid)
{
  f32x4 zero = {0.f, 0.f, 0.f, 0.f};
  f32x4 acc[2][4];
#pragma unroll
  for (int i = 0; i < 2; ++i)
#pragma unroll
    for (int f = 0; f < 4; ++f) acc[i][f] = zero;
  const int w = tid >> 6, l = tid & 63, u = l & 15, quad = l >> 4;
  kloop64<2, 4, 64>(d2p, HDIM, mb * 128, Wms, HDIM, HDIM, w * 32, 0, lds, acc, tid);
  float lsum = 0.f;
#pragma unroll
  for (int i = 0; i < 2; ++i)
#pragma unroll
    for (int j = 0; j < 4; ++j) {
      int row = mb * 128 + w * 32 + 16 * i + quad * 4 + j;
      const float* yr = y + ((size_t)tstep * BB + row) * YDIM;
#pragma unroll
      for (int f = 0; f < 2; ++f) {
        int c = 16 * f + u;
        float m  = acc[i][f][j] + mbias[c];
        float sp = acc[i][f + 2][j] + sbias[c];
        float sg = (sp > 20.f) ? sp : log1pf(expf(sp));
        float dv = (yr[c] - m) / sg;
        lsum += dv * dv + 2.f * logf(sg) + 1.8378770664093453f;
      }
    }
  lsum *= 0.5f;
#pragma unroll
  for (int o = 32; o; o >>= 1) lsum += __shfl_xor(lsum, o);
  if (l == 0) atomicAdd(nll, lsum);
}

// ---------------- prepack ----------------
__global__ __launch_bounds__(256) void prepack_kernel(
    const float* y, const float* dw1, const float* dw2,
    const float* mw, const float* sw,
    const float* wih0, const float* whh0, const float* bih0, const float* bhh0,
    const float* wih1, const float* whh1, const float* bih1, const float* bhh1,
    char* __restrict__ ws)
{
  const size_t g = (size_t)blockIdx.x * 256 + threadIdx.x;
  const size_t N = (size_t)gridDim.x * 256;
  // zero fp32 h state (4 bufs) and bf16 h copies (4 bufs)
  float4 z4 = {0.f, 0.f, 0.f, 0.f};
  float4* hz = (float4*)(ws + OFF_HAF);
  for (size_t i = g; i < (size_t)4 * BB * RDIM / 4; i += N) hz[i] = z4;
  int4 zi = {0, 0, 0, 0};
  int4* h16z = (int4*)(ws + OFF_HA16);
  for (size_t i = g; i < (size_t)4 * BB * RDIM / 8; i += N) h16z[i] = zi;
  if (g == 0) *(float*)(ws + OFF_NLL) = 0.f;

  short* y16  = (short*)(ws + OFF_Y16);
  short* Wg0i = (short*)(ws + OFF_WG0I);
  short* Wg0h = (short*)(ws + OFF_WG0H);
  short* Wg1i = (short*)(ws + OFF_WG1I);
  short* Wg1h = (short*)(ws + OFF_WG1H);
  short* Wd1  = (short*)(ws + OFF_WD1);
  short* Wd2  = (short*)(ws + OFF_WD2);
  short* Wms  = (short*)(ws + OFF_WMS);
  float* bi0  = (float*)(ws + OFF_BI0);
  float* bh0  = (float*)(ws + OFF_BH0);
  float* bi1  = (float*)(ws + OFF_BI1);
  float* bh1  = (float*)(ws + OFF_BH1);

  for (size_t s = g; s < (size_t)TT * BB * YDIM / 8; s += N)
    cvt8(y + s * 8, y16 + s * 8);
  for (size_t s = g; s < (size_t)1536 * RDIM / 8; s += N) {
    int row = (int)(s >> 6), seg = (int)(s & 63) << 3;
    int pr = permRow(row);
    cvt8(whh0 + (size_t)pr * RDIM + seg, Wg0h + (size_t)row * RDIM + seg);
    cvt8(wih1 + (size_t)pr * RDIM + seg, Wg1i + (size_t)row * RDIM + seg);
    cvt8(whh1 + (size_t)pr * RDIM + seg, Wg1h + (size_t)row * RDIM + seg);
  }
  for (size_t s = g; s < (size_t)1536 * YDIM / 8; s += N) {
    int row = (int)(s >> 2), seg = (int)(s & 3) << 3;
    cvt8(wih0 + (size_t)permRow(row) * YDIM + seg, Wg0i + (size_t)row * YDIM + seg);
  }
  for (size_t s = g; s < (size_t)HDIM * RDIM / 8; s += N)
    cvt8(dw1 + s * 8, Wd1 + s * 8);
  for (size_t s = g; s < (size_t)HDIM * HDIM / 8; s += N)
    cvt8(dw2 + s * 8, Wd2 + s * 8);
  for (size_t s = g; s < (size_t)64 * HDIM / 8; s += N) {
    int row = (int)(s >> 7), seg = (int)(s & 127) << 3;
    const float* src = (row < 32) ? (mw + (size_t)row * HDIM + seg)
                                  : (sw + (size_t)(row - 32) * HDIM + seg);
    cvt8(src, Wms + (size_t)row * HDIM + seg);
  }
  for (size_t s = g; s < 1536; s += N) {
    int pr = permRow((int)s);
    bi0[s] = bih0[pr]; bh0[s] = bhh0[pr];
    bi1[s] = bih1[pr]; bh1[s] = bhh1[pr];
  }
}

// ---------------- one pipeline phase (r0 proven mapping, 392 blocks) ----------------
__global__ __launch_bounds__(256, 2) void phase_kernel(
    int p, const float* __restrict__ y,
    const float* db1, const float* db2, const float* mbias, const float* sbias,
    char* __restrict__ ws)
{
  __shared__ short lds[2 * LDS_BUF];
  const int tid = threadIdx.x;
  const int t = blockIdx.x;
  const int cur = p & 1, prv = cur ^ 1;

  float* hAf = (float*)(ws + OFF_HAF);
  float* hBf = (float*)(ws + OFF_HBF);
  short* hA16 = (short*)(ws + OFF_HA16);
  short* hB16 = (short*)(ws + OFF_HB16);
  short* d10 = (short*)(ws + OFF_D1);
  short* d20 = (short*)(ws + OFF_D2);
  const short* y16 = (const short*)(ws + OFF_Y16);

  float* hAfc = hAf + (size_t)cur * BB * RDIM;
  float* hAfp = hAf + (size_t)prv * BB * RDIM;
  float* hBfc = hBf + (size_t)cur * BB * RDIM;
  float* hBfp = hBf + (size_t)prv * BB * RDIM;
  short* hA16c = hA16 + (size_t)cur * BB * RDIM;
  short* hA16p = hA16 + (size_t)prv * BB * RDIM;
  short* hB16c = hB16 + (size_t)cur * BB * RDIM;
  short* hB16p = hB16 + (size_t)prv * BB * RDIM;
  short* d1c = d10 + (size_t)cur * BB * HDIM;
  short* d1p = d10 + (size_t)prv * BB * HDIM;
  short* d2c = d20 + (size_t)cur * BB * HDIM;
  short* d2p = d20 + (size_t)prv * BB * HDIM;

  const short* Wg0i = (const short*)(ws + OFF_WG0I);
  const short* Wg0h = (const short*)(ws + OFF_WG0H);
  const short* Wg1i = (const short*)(ws + OFF_WG1I);
  const short* Wg1h = (const short*)(ws + OFF_WG1H);
  const short* Wd1  = (const short*)(ws + OFF_WD1);
  const short* Wd2  = (const short*)(ws + OFF_WD2);
  const short* Wms  = (const short*)(ws + OFF_WMS);
  const float* bi0  = (const float*)(ws + OFF_BI0);
  const float* bh0  = (const float*)(ws + OFF_BH0);
  const float* bi1  = (const float*)(ws + OFF_BI1);
  const float* bh1  = (const float*)(ws + OFF_BH1);
  float* nllp = (float*)(ws + OFF_NLL);

  if (t < 128) {                    // GRU1 -> h1_{p-1}
    if (p >= 1 && p <= 255) {
      int mb = t >> 4, nb = t & 15;
      gru_tile<false>(mb, nb,
                      hA16p, RDIM, Wg1i + (size_t)nb * 96 * RDIM,
                      hB16p, Wg1h + (size_t)nb * 96 * RDIM,
                      bi1, bh1, hBfp, hBfc, hB16c, lds, tid);
    }
  } else if (t < 192) {             // D2 for step p-2
    if (p >= 2 && p <= 257) {
      int q = t - 128, mb = q >> 3, nb = q & 7;
      dec_tile(mb, nb, d1p, HDIM, HDIM, Wd2 + (size_t)nb * 128 * HDIM,
               db2, d2c, lds, tid);
    }
  } else if (t < 200) {             // mean/std + nll for step p-3
    if (p >= 3 && p <= 258) {
      ms_tile(t - 192, p - 3, d2p, Wms, mbias, sbias, y, nllp, lds, tid);
    }
  } else if (t < 328) {             // GRU0 -> h0_p
    if (p <= 255) {
      int q = t - 200, mb = q >> 4, nb = q & 15;
      gru_tile<true>(mb, nb,
                     y16 + (size_t)p * BB * YDIM, YDIM, Wg0i + (size_t)nb * 96 * YDIM,
                     hA16p, Wg0h + (size_t)nb * 96 * RDIM,
                     bi0, bh0, hAfp, hAfc, hA16c, lds, tid);
    }
  } else {                          // D1 for step p-1
    if (p >= 1 && p <= 256) {
      int q = t - 328, mb = q >> 3, nb = q & 7;
      dec_tile(mb, nb, hB16p, RDIM, RDIM, Wd1 + (size_t)nb * 128 * RDIM,
               db1, d1c, lds, tid);
    }
  }
}

__global__ void finish_kernel(float* out, const char* ws)
{
  if (threadIdx.x == 0 && blockIdx.x == 0)
    out[0] = *(const float*)(ws + OFF_NLL);
}

extern "C" void kernel_launch(void* const* d_in, const int* in_sizes, int n_in,
                              void* d_out, int out_size, void* d_ws, size_t ws_size,
                              hipStream_t stream) {
  (void)in_sizes; (void)n_in; (void)out_size; (void)ws_size;
  const float* y    = (const float*)d_in[0];
  const float* dw1  = (const float*)d_in[1];
  const float* db1  = (const float*)d_in[2];
  const float* dw2  = (const float*)d_in[3];
  const float* db2  = (const float*)d_in[4];
  const float* mw   = (const float*)d_in[5];
  const float* mbias= (const float*)d_in[6];
  const float* sw   = (const float*)d_in[7];
  const float* sbias= (const float*)d_in[8];
  const float* wih0 = (const float*)d_in[9];
  const float* whh0 = (const float*)d_in[10];
  const float* bih0 = (const float*)d_in[11];
  const float* bhh0 = (const float*)d_in[12];
  const float* wih1 = (const float*)d_in[13];
  const float* whh1 = (const float*)d_in[14];
  const float* bih1 = (const float*)d_in[15];
  const float* bhh1 = (const float*)d_in[16];
  char* ws = (char*)d_ws;
  float* out = (float*)d_out;

  prepack_kernel<<<256, 256, 0, stream>>>(y, dw1, dw2, mw, sw,
                                          wih0, whh0, bih0, bhh0,
                                          wih1, whh1, bih1, bhh1, ws);
  for (int p = 0; p < 259; ++p)
    phase_kernel<<<392, 256, 0, stream>>>(p, y, db1, db2, mbias, sbias, ws);
  finish_kernel<<<1, 1, 0, stream>>>(out, ws);
}

// Round 5
// 5369.578 us; speedup vs baseline: 3.7002x; 1.0001x over previous
//
#include <hip/hip_runtime.h>
#include <math.h>

#define TT   256
#define BB   1024
#define YDIM 32
#define HDIM 1024
#define RDIM 512

typedef __attribute__((ext_vector_type(8))) short frag8;
typedef __attribute__((ext_vector_type(4))) float f32x4;

#define LDS_BUF 16384  // shorts per double-buffer half: (128 A rows + 128 B rows) x 64

// ---------------- workspace layout (bytes) ----------------
#define OFF_NLL   ((size_t)0)
#define OFF_HAF   ((size_t)4096)                     // fp32 h0 x2 (state)
#define SZ_HF     ((size_t)BB*RDIM*4)
#define OFF_HBF   (OFF_HAF + 2*SZ_HF)                // fp32 h1 x2
#define OFF_HA16  (OFF_HBF + 2*SZ_HF)                // bf16 h0 x2 (GEMM operand copy)
#define SZ_H16    ((size_t)BB*RDIM*2)
#define OFF_HB16  (OFF_HA16 + 2*SZ_H16)              // bf16 h1 x2
#define OFF_D1    (OFF_HB16 + 2*SZ_H16)              // bf16 d1 x2
#define SZ_DBUF   ((size_t)BB*HDIM*2)
#define OFF_D2    (OFF_D1 + 2*SZ_DBUF)               // bf16 d2 x2
#define OFF_Y16   (OFF_D2 + 2*SZ_DBUF)               // bf16 y [T,B,32]
#define OFF_WG0I  (OFF_Y16 + (size_t)TT*BB*YDIM*2)
#define OFF_WG0H  (OFF_WG0I + (size_t)1536*YDIM*2)
#define OFF_WG1I  (OFF_WG0H + (size_t)1536*RDIM*2)
#define OFF_WG1H  (OFF_WG1I + (size_t)1536*RDIM*2)
#define OFF_WD1   (OFF_WG1H + (size_t)1536*RDIM*2)
#define OFF_WD2   (OFF_WD1 + (size_t)HDIM*RDIM*2)
#define OFF_WMS   (OFF_WD2 + (size_t)HDIM*HDIM*2)
#define OFF_BI0   (OFF_WMS + (size_t)64*HDIM*2)
#define OFF_BH0   (OFF_BI0 + 1536*4)
#define OFF_BI1   (OFF_BH0 + 1536*4)
#define OFF_BH1   (OFF_BI1 + 1536*4)

__device__ __forceinline__ short f2bf(float f) {
  union { float f; unsigned u; } v; v.f = f;
  unsigned r = (v.u + 0x7fffu + ((v.u >> 16) & 1u)) >> 16;
  return (short)r;
}
__device__ __forceinline__ void cvt8(const float* s, short* d) {
  float4 a = *(const float4*)s;
  float4 b = *(const float4*)(s + 4);
  frag8 v;
  v[0]=f2bf(a.x); v[1]=f2bf(a.y); v[2]=f2bf(a.z); v[3]=f2bf(a.w);
  v[4]=f2bf(b.x); v[5]=f2bf(b.y); v[6]=f2bf(b.z); v[7]=f2bf(b.w);
  *(frag8*)d = v;
}
// gate-interleaved row permutation: packed row n = q*48 + g*16 + u  <->  src row g*512 + q*16 + u
__device__ __forceinline__ int permRow(int n) {
  int q = n / 48, r = n - 48 * q, g = r >> 4, u = r & 15;
  return g * 512 + q * 16 + u;
}
__device__ __forceinline__ float sigf(float x) { return 1.0f / (1.0f + expf(-x)); }

// async 16B global -> LDS (dest = uniform base + lane*16)
__device__ __forceinline__ void gload16(const short* g, short* l) {
  __builtin_amdgcn_global_load_lds(
      (const __attribute__((address_space(1))) void*)g,
      (__attribute__((address_space(3))) void*)l, 16, 0, 0);
}

// counted vmcnt wait (literal immediates; "memory" keeps loads/reads ordered)
template<int N> __device__ __forceinline__ void waitv() {
  if constexpr (N == 0)      asm volatile("s_waitcnt vmcnt(0)" ::: "memory");
  else if constexpr (N == 6) asm volatile("s_waitcnt vmcnt(6)" ::: "memory");
  else if constexpr (N == 7) asm volatile("s_waitcnt vmcnt(7)" ::: "memory");
  else if constexpr (N == 8) asm volatile("s_waitcnt vmcnt(8)" ::: "memory");
  else                       asm volatile("s_waitcnt vmcnt(0)" ::: "memory");
}

// ---------------- double-buffered MFMA K-loop, 64-wide chunks ----------------
// A: bf16 [*, lda], 128 rows from m0. B: prepacked bf16 [NROWSB, ldb].
// LDS tile layout: 16B unit p = row*8 + (q ^ (row&7)), q = logical 8-elem segment.
//
// Counted-vmcnt pipeline (T4): per iteration we issue stage(kc+1) and then wait
// vmcnt(LPS) — draining only stage(kc), leaving stage(kc+1) in flight across the
// barrier. Successive stage latencies overlap 2-deep (T ~= L/2).
// LPS = loads/wave/stage = 4 (A) + NROWSB/32 (B); uniform across waves.
template<int MF, int NF, int NROWSB>
__device__ __forceinline__ void kloop64(
    const short* __restrict__ A, int lda, int m0,
    const short* __restrict__ B, int ldb, int K,
    int wm, int wn, short* lds, f32x4 (*acc)[NF], int tid)
{
  const int l = tid & 63, w = tid >> 6, u = l & 15, quad = l >> 4;
  const int nk = K >> 6;                 // always even (8 or 16)
  constexpr int BUNITS = NROWSB << 3;
  constexpr int LPS = 4 + NROWSB / 32;   // 96->7, 128->8, 64->6

  auto stage = [&](int kc, int buf) {
    short* base = lds + buf * LDS_BUF;
    const int k0 = kc << 6;
    for (int c = (w << 6); c < 1024; c += 256) {
      int p = c + l, r = p >> 3, q = (p & 7) ^ (r & 7);
      gload16(A + (size_t)(m0 + r) * lda + k0 + (q << 3), base + (c << 3));
    }
    short* bb = base + 8192;
    for (int c = (w << 6); c < BUNITS; c += 256) {
      int p = c + l, r = p >> 3, q = (p & 7) ^ (r & 7);
      gload16(B + (size_t)r * ldb + k0 + (q << 3), bb + (c << 3));
    }
  };

  stage(0, 0);
  for (int kc = 0; kc < nk; ++kc) {
    // read-guard: all waves finished ds_reads of buf[(kc+1)&1] (compute kc-1)
    asm volatile("s_waitcnt lgkmcnt(0)" ::: "memory");
    __builtin_amdgcn_s_barrier();
    if (kc + 1 < nk) {
      stage(kc + 1, (kc + 1) & 1);       // issue next; stays in flight past barrier
      waitv<LPS>();                      // only stage(kc) must have landed
    } else {
      waitv<0>();                        // last chunk: drain it
    }
    __builtin_amdgcn_s_barrier();        // stage(kc) visible to all waves
    asm volatile("" ::: "memory");       // no LDS read hoists above the barrier
    const short* base = lds + (kc & 1) * LDS_BUF;
#pragma unroll
    for (int kk2 = 0; kk2 < 2; ++kk2) {
      const int q = (kk2 << 2) + quad;
      const int aoff = (q ^ (u & 7)) << 3;
      frag8 a[MF], b[NF];
#pragma unroll
      for (int i = 0; i < MF; ++i)
        a[i] = *(const frag8*)(base + ((wm + (i << 4) + u) << 6) + aoff);
#pragma unroll
      for (int f = 0; f < NF; ++f)
        b[f] = *(const frag8*)(base + 8192 + ((wn + (f << 4) + u) << 6) + aoff);
#pragma unroll
      for (int i = 0; i < MF; ++i)
#pragma unroll
        for (int f = 0; f < NF; ++f)
          acc[i][f] = __builtin_amdgcn_mfma_f32_16x16x32_bf16(a[i], b[f], acc[i][f], 0, 0, 0);
    }
  }
}

// single 32-wide chunk (GRU layer0 gi, K=32)
template<int MF, int NF>
__device__ __forceinline__ void kloop32(
    const short* __restrict__ A, int lda, int m0,
    const short* __restrict__ B, int nrowsB,
    int wm, int wn, short* lds, f32x4 (*acc)[NF], int tid)
{
  const int l = tid & 63, w = tid >> 6, u = l & 15, quad = l >> 4;
  short* base = lds;
  for (int c = (w << 6); c < 512; c += 256) {
    int p = c + l, r = p >> 2, q = (p & 3) ^ (r & 3);
    gload16(A + (size_t)(m0 + r) * lda + (q << 3), base + (c << 3));
  }
  short* bb = base + 4096;
  const int bunits = nrowsB << 2;
  for (int c = (w << 6); c < bunits; c += 256) {
    int p = c + l, r = p >> 2, q = (p & 3) ^ (r & 3);
    gload16(B + (size_t)r * 32 + (q << 3), bb + (c << 3));
  }
  __syncthreads();
  const int aoff = (quad ^ (u & 3)) << 3;
  frag8 a[MF], b[NF];
#pragma unroll
  for (int i = 0; i < MF; ++i)
    a[i] = *(const frag8*)(base + ((wm + (i << 4) + u) << 5) + aoff);
#pragma unroll
  for (int f = 0; f < NF; ++f)
    b[f] = *(const frag8*)(base + 4096 + ((wn + (f << 4) + u) << 5) + aoff);
#pragma unroll
  for (int i = 0; i < MF; ++i)
#pragma unroll
    for (int f = 0; f < NF; ++f)
      acc[i][f] = __builtin_amdgcn_mfma_f32_16x16x32_bf16(a[i], b[f], acc[i][f], 0, 0, 0);
  __syncthreads();
}

// ---------------- GRU tile ----------------
template<bool GI32>
__device__ void gru_tile(int mb, int nb,
                         const short* Ax, int ldx, const short* Wgi,
                         const short* Ah, const short* Wgh,
                         const float* bi, const float* bh,
                         const float* hold, float* hout, short* h16out,
                         short* lds, int tid)
{
  f32x4 zero = {0.f, 0.f, 0.f, 0.f};
  f32x4 gi[4][3], gh[4][3];
#pragma unroll
  for (int i = 0; i < 4; ++i)
#pragma unroll
    for (int f = 0; f < 3; ++f) { gi[i][f] = zero; gh[i][f] = zero; }
  const int w = tid >> 6, l = tid & 63, u = l & 15, quad = l >> 4;
  const int wm = (w & 1) * 64, wn = (w >> 1) * 48;
  if (GI32)
    kloop32<4, 3>(Ax, ldx, mb * 128, Wgi, 96, wm, wn, lds, gi, tid);
  else
    kloop64<4, 3, 96>(Ax, ldx, mb * 128, Wgi, RDIM, RDIM, wm, wn, lds, gi, tid);
  kloop64<4, 3, 96>(Ah, RDIM, mb * 128, Wgh, RDIM, RDIM, wm, wn, lds, gh, tid);

  const int np = nb * 96 + (w >> 1) * 48 + u;
  const float bir = bi[np], biz = bi[np + 16], bin = bi[np + 32];
  const float bhr = bh[np], bhz = bh[np + 16], bhn = bh[np + 32];
  const int unit = nb * 32 + (w >> 1) * 16 + u;
#pragma unroll
  for (int i = 0; i < 4; ++i)
#pragma unroll
    for (int j = 0; j < 4; ++j) {
      int row = mb * 128 + wm + 16 * i + quad * 4 + j;
      float r = sigf((gi[i][0][j] + bir) + (gh[i][0][j] + bhr));
      float z = sigf((gi[i][1][j] + biz) + (gh[i][1][j] + bhz));
      float n = tanhf((gi[i][2][j] + bin) + r * (gh[i][2][j] + bhn));
      float ho = hold[(size_t)row * RDIM + unit];
      float hn = (1.f - z) * n + z * ho;
      hout[(size_t)row * RDIM + unit] = hn;
      h16out[(size_t)row * RDIM + unit] = f2bf(hn);
    }
}

// ---------------- decoder Linear+ReLU tile (128x128) ----------------
__device__ void dec_tile(int mb, int nb, const short* A, int lda, int K,
                         const short* W, const float* bias, short* outp,
                         short* lds, int tid)
{
  f32x4 zero = {0.f, 0.f, 0.f, 0.f};
  f32x4 acc[4][4];
#pragma unroll
  for (int i = 0; i < 4; ++i)
#pragma unroll
    for (int f = 0; f < 4; ++f) acc[i][f] = zero;
  const int w = tid >> 6, l = tid & 63, u = l & 15, quad = l >> 4;
  const int wm = (w & 1) * 64, wn = (w >> 1) * 64;
  kloop64<4, 4, 128>(A, lda, mb * 128, W, K, K, wm, wn, lds, acc, tid);
  const int colb = nb * 128 + wn + u;
  float bv[4];
#pragma unroll
  for (int f = 0; f < 4; ++f) bv[f] = bias[colb + 16 * f];
#pragma unroll
  for (int i = 0; i < 4; ++i)
#pragma unroll
    for (int f = 0; f < 4; ++f)
#pragma unroll
      for (int j = 0; j < 4; ++j) {
        int row = mb * 128 + wm + 16 * i + quad * 4 + j;
        float v = acc[i][f][j] + bv[f];
        if (v < 0.f) v = 0.f;
        outp[(size_t)row * HDIM + colb + 16 * f] = f2bf(v);
      }
}

// ---------------- mean/std + gaussian NLL tile ----------------
__device__ void ms_tile(int mb, int tstep, const short* d2p, const short* Wms,
                        const float* mbias, const float* sbias, const float* y,
                        float* nll, short* lds, int tid)
{
  f32x4 zero = {0.f, 0.f, 0.f, 0.f};
  f32x4 acc[2][4];
#pragma unroll
  for (int i = 0; i < 2; ++i)
#pragma unroll
    for (int f = 0; f < 4; ++f) acc[i][f] = zero;
  const int w = tid >> 6, l = tid & 63, u = l & 15, quad = l >> 4;
  kloop64<2, 4, 64>(d2p, HDIM, mb * 128, Wms, HDIM, HDIM, w * 32, 0, lds, acc, tid);
  float lsum = 0.f;
#pragma unroll
  for (int i = 0; i < 2; ++i)
#pragma unroll
    for (int j = 0; j < 4; ++j) {
      int row = mb * 128 + w * 32 + 16 * i + quad * 4 + j;
      const float* yr = y + ((size_t)tstep * BB + row) * YDIM;
#pragma unroll
      for (int f = 0; f < 2; ++f) {
        int c = 16 * f + u;
        float m  = acc[i][f][j] + mbias[c];
        float sp = acc[i][f + 2][j] + sbias[c];
        float sg = (sp > 20.f) ? sp : log1pf(expf(sp));
        float dv = (yr[c] - m) / sg;
        lsum += dv * dv + 2.f * logf(sg) + 1.8378770664093453f;
      }
    }
  lsum *= 0.5f;
#pragma unroll
  for (int o = 32; o; o >>= 1) lsum += __shfl_xor(lsum, o);
  if (l == 0) atomicAdd(nll, lsum);
}

// ---------------- prepack ----------------
__global__ __launch_bounds__(256) void prepack_kernel(
    const float* y, const float* dw1, const float* dw2,
    const float* mw, const float* sw,
    const float* wih0, const float* whh0, const float* bih0, const float* bhh0,
    const float* wih1, const float* whh1, const float* bih1, const float* bhh1,
    char* __restrict__ ws)
{
  const size_t g = (size_t)blockIdx.x * 256 + threadIdx.x;
  const size_t N = (size_t)gridDim.x * 256;
  // zero fp32 h state (4 bufs) and bf16 h copies (4 bufs)
  float4 z4 = {0.f, 0.f, 0.f, 0.f};
  float4* hz = (float4*)(ws + OFF_HAF);
  for (size_t i = g; i < (size_t)4 * BB * RDIM / 4; i += N) hz[i] = z4;
  int4 zi = {0, 0, 0, 0};
  int4* h16z = (int4*)(ws + OFF_HA16);
  for (size_t i = g; i < (size_t)4 * BB * RDIM / 8; i += N) h16z[i] = zi;
  if (g == 0) *(float*)(ws + OFF_NLL) = 0.f;

  short* y16  = (short*)(ws + OFF_Y16);
  short* Wg0i = (short*)(ws + OFF_WG0I);
  short* Wg0h = (short*)(ws + OFF_WG0H);
  short* Wg1i = (short*)(ws + OFF_WG1I);
  short* Wg1h = (short*)(ws + OFF_WG1H);
  short* Wd1  = (short*)(ws + OFF_WD1);
  short* Wd2  = (short*)(ws + OFF_WD2);
  short* Wms  = (short*)(ws + OFF_WMS);
  float* bi0  = (float*)(ws + OFF_BI0);
  float* bh0  = (float*)(ws + OFF_BH0);
  float* bi1  = (float*)(ws + OFF_BI1);
  float* bh1  = (float*)(ws + OFF_BH1);

  for (size_t s = g; s < (size_t)TT * BB * YDIM / 8; s += N)
    cvt8(y + s * 8, y16 + s * 8);
  for (size_t s = g; s < (size_t)1536 * RDIM / 8; s += N) {
    int row = (int)(s >> 6), seg = (int)(s & 63) << 3;
    int pr = permRow(row);
    cvt8(whh0 + (size_t)pr * RDIM + seg, Wg0h + (size_t)row * RDIM + seg);
    cvt8(wih1 + (size_t)pr * RDIM + seg, Wg1i + (size_t)row * RDIM + seg);
    cvt8(whh1 + (size_t)pr * RDIM + seg, Wg1h + (size_t)row * RDIM + seg);
  }
  for (size_t s = g; s < (size_t)1536 * YDIM / 8; s += N) {
    int row = (int)(s >> 2), seg = (int)(s & 3) << 3;
    cvt8(wih0 + (size_t)permRow(row) * YDIM + seg, Wg0i + (size_t)row * YDIM + seg);
  }
  for (size_t s = g; s < (size_t)HDIM * RDIM / 8; s += N)
    cvt8(dw1 + s * 8, Wd1 + s * 8);
  for (size_t s = g; s < (size_t)HDIM * HDIM / 8; s += N)
    cvt8(dw2 + s * 8, Wd2 + s * 8);
  for (size_t s = g; s < (size_t)64 * HDIM / 8; s += N) {
    int row = (int)(s >> 7), seg = (int)(s & 127) << 3;
    const float* src = (row < 32) ? (mw + (size_t)row * HDIM + seg)
                                  : (sw + (size_t)(row - 32) * HDIM + seg);
    cvt8(src, Wms + (size_t)row * HDIM + seg);
  }
  for (size_t s = g; s < 1536; s += N) {
    int pr = permRow((int)s);
    bi0[s] = bih0[pr]; bh0[s] = bhh0[pr];
    bi1[s] = bih1[pr]; bh1[s] = bhh1[pr];
  }
}

// ---------------- one pipeline phase ----------------
// XCD-cell mapping: HW round-robins blockIdx across XCDs (xcd = t&7). Each XCD
// gets a SQUARE cell of every role's tile grid so both operands stay local:
//   GRU1/GRU0 (8mb x 16nb): cell 4mb x 4nb   -> A replicated in 4 L2s, B in 2
//   D2/D1     (8mb x  8nb): cell 4mb x 2nb   -> A in 2 L2s, B in 4
//   ms: 1 tile per XCD
// Cuts cross-XCD operand amplification: L3 reads ~62 -> ~44 MB/phase.
// 49 slots per XCD, identical role mix -> balanced.
__global__ __launch_bounds__(256, 2) void phase_kernel(
    int p, const float* __restrict__ y,
    const float* db1, const float* db2, const float* mbias, const float* sbias,
    char* __restrict__ ws)
{
  __shared__ short lds[2 * LDS_BUF];
  const int tid = threadIdx.x;
  const int xcd = blockIdx.x & 7;
  const int s = blockIdx.x >> 3;
  const int cur = p & 1, prv = cur ^ 1;

  float* hAf = (float*)(ws + OFF_HAF);
  float* hBf = (float*)(ws + OFF_HBF);
  short* hA16 = (short*)(ws + OFF_HA16);
  short* hB16 = (short*)(ws + OFF_HB16);
  short* d10 = (short*)(ws + OFF_D1);
  short* d20 = (short*)(ws + OFF_D2);
  const short* y16 = (const short*)(ws + OFF_Y16);

  float* hAfc = hAf + (size_t)cur * BB * RDIM;
  float* hAfp = hAf + (size_t)prv * BB * RDIM;
  float* hBfc = hBf + (size_t)cur * BB * RDIM;
  float* hBfp = hBf + (size_t)prv * BB * RDIM;
  short* hA16c = hA16 + (size_t)cur * BB * RDIM;
  short* hA16p = hA16 + (size_t)prv * BB * RDIM;
  short* hB16c = hB16 + (size_t)cur * BB * RDIM;
  short* hB16p = hB16 + (size_t)prv * BB * RDIM;
  short* d1c = d10 + (size_t)cur * BB * HDIM;
  short* d1p = d10 + (size_t)prv * BB * HDIM;
  short* d2c = d20 + (size_t)cur * BB * HDIM;
  short* d2p = d20 + (size_t)prv * BB * HDIM;

  const short* Wg0i = (const short*)(ws + OFF_WG0I);
  const short* Wg0h = (const short*)(ws + OFF_WG0H);
  const short* Wg1i = (const short*)(ws + OFF_WG1I);
  const short* Wg1h = (const short*)(ws + OFF_WG1H);
  const short* Wd1  = (const short*)(ws + OFF_WD1);
  const short* Wd2  = (const short*)(ws + OFF_WD2);
  const short* Wms  = (const short*)(ws + OFF_WMS);
  const float* bi0  = (const float*)(ws + OFF_BI0);
  const float* bh0  = (const float*)(ws + OFF_BH0);
  const float* bi1  = (const float*)(ws + OFF_BI1);
  const float* bh1  = (const float*)(ws + OFF_BH1);
  float* nllp = (float*)(ws + OFF_NLL);

  if (s < 16) {                     // GRU1 -> h1_{p-1}: cell 4mb x 4nb
    if (p >= 1 && p <= 255) {
      int mb = 4 * (xcd & 1) + (s & 3);
      int nb = 4 * (xcd >> 1) + (s >> 2);
      gru_tile<false>(mb, nb,
                      hA16p, RDIM, Wg1i + (size_t)nb * 96 * RDIM,
                      hB16p, Wg1h + (size_t)nb * 96 * RDIM,
                      bi1, bh1, hBfp, hBfc, hB16c, lds, tid);
    }
  } else if (s < 32) {              // GRU0 -> h0_p: cell 4mb x 4nb
    if (p <= 255) {
      int q = s - 16;
      int mb = 4 * (xcd & 1) + (q & 3);
      int nb = 4 * (xcd >> 1) + (q >> 2);
      gru_tile<true>(mb, nb,
                     y16 + (size_t)p * BB * YDIM, YDIM, Wg0i + (size_t)nb * 96 * YDIM,
                     hA16p, Wg0h + (size_t)nb * 96 * RDIM,
                     bi0, bh0, hAfp, hAfc, hA16c, lds, tid);
    }
  } else if (s < 40) {              // D2 for step p-2: cell 4mb x 2nb
    if (p >= 2 && p <= 257) {
      int q = s - 32;
      int mb = 4 * (xcd & 1) + (q & 3);
      int nb = 2 * (xcd >> 1) + (q >> 2);
      dec_tile(mb, nb, d1p, HDIM, HDIM, Wd2 + (size_t)nb * 128 * HDIM,
               db2, d2c, lds, tid);
    }
  } else if (s < 48) {              // D1 for step p-1: cell 4mb x 2nb
    if (p >= 1 && p <= 256) {
      int q = s - 40;
      int mb = 4 * (xcd & 1) + (q & 3);
      int nb = 2 * (xcd >> 1) + (q >> 2);
      dec_tile(mb, nb, hB16p, RDIM, RDIM, Wd1 + (size_t)nb * 128 * RDIM,
               db1, d1c, lds, tid);
    }
  } else {                          // mean/std + nll for step p-3: 1 tile/XCD
    if (p >= 3 && p <= 258) {
      ms_tile(xcd, p - 3, d2p, Wms, mbias, sbias, y, nllp, lds, tid);
    }
  }
}

__global__ void finish_kernel(float* out, const char* ws)
{
  if (threadIdx.x == 0 && blockIdx.x == 0)
    out[0] = *(const float*)(ws + OFF_NLL);
}

extern "C" void kernel_launch(void* const* d_in, const int* in_sizes, int n_in,
                              void* d_out, int out_size, void* d_ws, size_t ws_size,
                              hipStream_t stream) {
  (void)in_sizes; (void)n_in; (void)out_size; (void)ws_size;
  const float* y    = (const float*)d_in[0];
  const float* dw1  = (const float*)d_in[1];
  const float* db1  = (const float*)d_in[2];
  const float* dw2  = (const float*)d_in[3];
  const float* db2  = (const float*)d_in[4];
  const float* mw   = (const float*)d_in[5];
  const float* mbias= (const float*)d_in[6];
  const float* sw   = (const float*)d_in[7];
  const float* sbias= (const float*)d_in[8];
  const float* wih0 = (const float*)d_in[9];
  const float* whh0 = (const float*)d_in[10];
  const float* bih0 = (const float*)d_in[11];
  const float* bhh0 = (const float*)d_in[12];
  const float* wih1 = (const float*)d_in[13];
  const float* whh1 = (const float*)d_in[14];
  const float* bih1 = (const float*)d_in[15];
  const float* bhh1 = (const float*)d_in[16];
  char* ws = (char*)d_ws;
  float* out = (float*)d_out;

  prepack_kernel<<<256, 256, 0, stream>>>(y, dw1, dw2, mw, sw,
                                          wih0, whh0, bih0, bhh0,
                                          wih1, whh1, bih1, bhh1, ws);
  for (int p = 0; p < 259; ++p)
    phase_kernel<<<392, 256, 0, stream>>>(p, y, db1, db2, mbias, sbias, ws);
  finish_kernel<<<1, 1, 0, stream>>>(out, ws);
}